// Round 10
// baseline (297.894 us; speedup 1.0000x reference)
//
#include <hip/hip_runtime.h>
#include <math.h>

// Problem constants (B=2, T=8, H=W=56, C=128, heads=8, hd=16, WS=7, nh=nw=8)
constexpr int H_   = 56;
constexpr int HW_  = 56 * 56;          // 3136
constexpr int NPIX = 8 * HW_;          // 25088 (per batch)
constexpr int SLAB = 128 * HW_ * 16;   // floats per q/k/v buffer

typedef __attribute__((ext_vector_type(8))) short bf16x8;
typedef __attribute__((ext_vector_type(4))) float f32x4;
typedef __attribute__((ext_vector_type(4))) unsigned int u32x4;

__device__ __forceinline__ unsigned short f2bf(float x) {
  unsigned int u = __float_as_uint(x);
  unsigned int r = (u + 0x7fffu + ((u >> 16) & 1u)) >> 16;
  return (unsigned short)r;
}
__device__ __forceinline__ float bf2f(unsigned short h) {
  return __uint_as_float(((unsigned int)h) << 16);
}

// ---------------------------------------------------------------------------
// GEMM: unchanged (K1 qkv+l2norm+scatter, K3 proj). ~52us combined.
// ---------------------------------------------------------------------------
template <int MODE>
__global__ __launch_bounds__(256, 3) void gemm128(
    const float* X, const float* __restrict__ Wt, const float* __restrict__ bias,
    float* __restrict__ Yq, float* __restrict__ Yk, float* __restrict__ Yv,
    float* Yout)
{
  __shared__ float xT[32][132];
  __shared__ float wT[32][132];
  const int tid = threadIdx.x;
  const int tx = tid & 15, ty = tid >> 4;
  const int mbase = blockIdx.x * 128;
  const int nt = (MODE == 0) ? (int)blockIdx.y : 0;
  const float* Wp = Wt + (size_t)nt * (128 * 128);

  float acc[8][8];
#pragma unroll
  for (int i = 0; i < 8; ++i)
#pragma unroll
    for (int j = 0; j < 8; ++j) acc[i][j] = 0.f;

  const int srow = tid >> 3;
  const int scol = (tid & 7) * 4;

  for (int kt = 0; kt < 4; ++kt) {
    if (kt) __syncthreads();
#pragma unroll
    for (int p = 0; p < 4; ++p) {
      int r = p * 32 + srow;
      float4 vx = *(const float4*)&X [(size_t)(mbase + r) * 128 + kt * 32 + scol];
      float4 vw = *(const float4*)&Wp[(size_t)r * 128 + kt * 32 + scol];
      xT[scol + 0][r] = vx.x; xT[scol + 1][r] = vx.y; xT[scol + 2][r] = vx.z; xT[scol + 3][r] = vx.w;
      wT[scol + 0][r] = vw.x; wT[scol + 1][r] = vw.y; wT[scol + 2][r] = vw.z; wT[scol + 3][r] = vw.w;
    }
    __syncthreads();
#pragma unroll 4
    for (int c = 0; c < 32; ++c) {
      float4 a0 = *(const float4*)&xT[c][tx * 4];
      float4 a1 = *(const float4*)&xT[c][64 + tx * 4];
      float4 b0 = *(const float4*)&wT[c][ty * 4];
      float4 b1 = *(const float4*)&wT[c][64 + ty * 4];
      float a[8] = {a0.x, a0.y, a0.z, a0.w, a1.x, a1.y, a1.z, a1.w};
      float b[8] = {b0.x, b0.y, b0.z, b0.w, b1.x, b1.y, b1.z, b1.w};
#pragma unroll
      for (int i = 0; i < 8; ++i)
#pragma unroll
        for (int j = 0; j < 8; ++j) acc[i][j] += a[i] * b[j];
    }
  }

  if (MODE == 0) {
    const int hq = ty >> 2;
    const int cq = (ty & 3) * 4;
    float* Ybase = (nt == 0) ? Yq : ((nt == 1) ? Yk : Yv);
#pragma unroll
    for (int i = 0; i < 8; ++i) {
      int gpix = mbase + ((i < 4) ? (tx * 4 + i) : (64 + tx * 4 + (i - 4)));
      int b = gpix / NPIX;
      int rem = gpix - b * NPIX;
      int t = rem / HW_;
      int s = rem - t * HW_;
      float s0 = acc[i][0]*acc[i][0] + acc[i][1]*acc[i][1] + acc[i][2]*acc[i][2] + acc[i][3]*acc[i][3];
      float s1 = acc[i][4]*acc[i][4] + acc[i][5]*acc[i][5] + acc[i][6]*acc[i][6] + acc[i][7]*acc[i][7];
      s0 += __shfl_xor(s0, 16); s0 += __shfl_xor(s0, 32);
      s1 += __shfl_xor(s1, 16); s1 += __shfl_xor(s1, 32);
      float r0 = 1.f, r1 = 1.f;
      if (nt < 2) {
        r0 = 1.f / fmaxf(sqrtf(s0), 1e-12f);
        r1 = 1.f / fmaxf(sqrtf(s1), 1e-12f);
      }
      int bt0 = (b * 8 + hq) * 8 + t;
      int bt1 = (b * 8 + hq + 4) * 8 + t;
      float* d0 = Ybase + ((size_t)bt0 * HW_ + s) * 16 + cq;
      float* d1 = Ybase + ((size_t)bt1 * HW_ + s) * 16 + cq;
      *(float4*)d0 = make_float4(acc[i][0]*r0, acc[i][1]*r0, acc[i][2]*r0, acc[i][3]*r0);
      *(float4*)d1 = make_float4(acc[i][4]*r1, acc[i][5]*r1, acc[i][6]*r1, acc[i][7]*r1);
    }
  } else {
    float4 bb0 = *(const float4*)&bias[ty * 4];
    float4 bb1 = *(const float4*)&bias[64 + ty * 4];
#pragma unroll
    for (int i = 0; i < 8; ++i) {
      int gpix = mbase + ((i < 4) ? (tx * 4 + i) : (64 + tx * 4 + (i - 4)));
      float* dst = Yout + (size_t)gpix * 128;
      *(float4*)&dst[ty * 4]      = make_float4(acc[i][0]+bb0.x, acc[i][1]+bb0.y, acc[i][2]+bb0.z, acc[i][3]+bb0.w);
      *(float4*)&dst[64 + ty * 4] = make_float4(acc[i][4]+bb1.x, acc[i][5]+bb1.y, acc[i][6]+bb1.z, acc[i][7]+bb1.w);
    }
  }
}

// ---------------------------------------------------------------------------
// MFMA window attention v8: TWO INDEPENDENT windows per 128-thread block.
// Evidence (R3/R4/R5/R9 vs R2/R6): single-wave 64-thread workgroups cap at
// ~10 WGs/CU regardless of LDS; 128-thread blocks reach 13-18 waves. Each
// wave here runs the round-9 proven body verbatim (84 VGPR, zero barriers,
// zero cross-wave traffic) on its own window, with its own 10,240 B LDS
// slice. LDS 20,480 B/block -> 7 blocks x 2 waves = ~14 waves/CU (vs 10).
// Corr d-loop unroll 2 -> 4 (more L2 loads in flight). No launch_bounds
// minimum (tight caps triggered the R6-8 unified-RF spill pathology).
// Math identical: coalesced corr, split-bf16 gram, Cauchy-Schwarz shift,
// Pb aliases cwf, qf direct from global, XCD pinning.
// ---------------------------------------------------------------------------
__global__ __launch_bounds__(128) void attn_mfma(
    const float* __restrict__ qn, const float* __restrict__ kn, const float* __restrict__ vv,
    const float* __restrict__ pos1, const float* __restrict__ pos2,
    float* __restrict__ mid)
{
  __shared__ __align__(16) unsigned char smem[2][10240];
  const int tid  = threadIdx.x;
  const int wave = tid >> 6;
  const int lane = tid & 63;
  unsigned char* sl = smem[wave];
  float*          cwf  = (float*)sl;                    // [49][52] f32 corr (phase 1)
  unsigned short* Pb   = (unsigned short*)sl;           // [49][72] bf16 (aliases cwf; 7056 B)
  float*          mi_s = (float*)(sl + 7104);           // [49] (dead-cwf tail)
  float*          scm  = (float*)(sl + 7304);           // [49]
  float*          sca  = (float*)(sl + 7504);           // [49]

  const int lg = lane >> 4;       // mfma k-group
  const int lr = lane & 15;       // mfma row/col within tile
  const int c4  = lane & 3;       // corr: channel quarter
  const int ilg = lane >> 2;      // corr: row within pass / d within row-48 sweep
  // XCD-aware remap: 4096 blocks, xcd = bid&7 -> 512 blocks/XCD = 16 bt-groups;
  // wave picks one of the block's two windows.
  const int bid = blockIdx.x;
  const int xcd = bid & 7;
  const int j = bid >> 3;                     // 0..511
  const int bt = xcd * 16 + (j >> 5);         // bt-group pinned to one XCD
  const int win = ((j & 31) << 1) | wave;     // 0..63
  const int wy = win >> 3;
  const int wx = win & 7;
  const int t = bt & 7;
  const int btk = bt - t + ((t < 7) ? (t + 1) : 7);
  const float* qb = qn + (size_t)bt  * (HW_ * 16);
  const float* kb = kn + (size_t)btk * (HW_ * 16);
  const float* vb = vv + (size_t)bt  * (HW_ * 16);

  const bool rowok = (lane < 49);
  const int il = rowok ? lane : 48;

  // ---- P1: correlation, coalesced. Passes p=0..2 cover rows 0..47. ----
  float diiv[3];
#pragma unroll
  for (int p = 0; p < 3; ++p) {
    const int il2 = p * 16 + ilg;            // 0..47
    const int ia2 = (il2 * 37) >> 8;         // il2/7
    const int ib2 = il2 - ia2 * 7;
    const int qh2 = ia2 * 8 + wy;
    const int qw2 = ib2 * 8 + wx;
    const f32x4 qv = *(const f32x4*)(qb + (size_t)(qh2 * 56 + qw2) * 16 + c4 * 4);
    float dii = 0.f;
    const float* p1r = pos1 + il2 * 49;
    float* cwr = cwf + il2 * 52;
#pragma unroll 4
    for (int d = 0; d < 49; ++d) {
      const int du = (d * 37) >> 8, dv = d - du * 7;
      const int hh = qh2 + du - 3, ww = qw2 + dv - 3;
      float pd = 0.f;
      if ((unsigned)hh < 56u && (unsigned)ww < 56u) {
        const f32x4 kv = *(const f32x4*)(kb + (size_t)(hh * 56 + ww) * 16 + c4 * 4);
        pd = fmaf(qv.x, kv.x, fmaf(qv.y, kv.y, fmaf(qv.z, kv.z, qv.w * kv.w)));
      }
      pd += __shfl_xor(pd, 1);
      pd += __shfl_xor(pd, 2);
      const float val = pd + p1r[d];
      dii += val * val;
      if (c4 == 0) cwr[d] = val;
    }
    diiv[p] = dii;
  }

  // ---- row 48 sweep: lanes = (c4, d-group) ----
  float dii48;
  {
    const int qh2 = 48 + wy, qw2 = 48 + wx;
    const f32x4 qv = *(const f32x4*)(qb + (size_t)(qh2 * 56 + qw2) * 16 + c4 * 4);
    float dacc = 0.f;
#pragma unroll
    for (int dp = 0; dp < 4; ++dp) {
      const int d = dp * 16 + ilg;
      const bool dok = (d < 49);
      const int dc = dok ? d : 0;
      const int du = (dc * 37) >> 8, dv = dc - du * 7;
      const int hh = qh2 + du - 3, ww = qw2 + dv - 3;
      float pd = 0.f;
      if (dok && (unsigned)hh < 56u && (unsigned)ww < 56u) {
        const f32x4 kv = *(const f32x4*)(kb + (size_t)(hh * 56 + ww) * 16 + c4 * 4);
        pd = fmaf(qv.x, kv.x, fmaf(qv.y, kv.y, fmaf(qv.z, kv.z, qv.w * kv.w)));
      }
      pd += __shfl_xor(pd, 1);
      pd += __shfl_xor(pd, 2);
      if (dok) {
        const float val = pd + pos1[48 * 49 + dc];
        dacc += val * val;
        if (c4 == 0) cwf[48 * 52 + dc] = val;
      }
    }
    dacc += __shfl_xor(dacc, 4);
    dacc += __shfl_xor(dacc, 8);
    dacc += __shfl_xor(dacc, 16);
    dacc += __shfl_xor(dacc, 32);
    dii48 = dacc;
  }

  // ---- issue V loads NOW (raw f32, packed after Sm phase) ----
  float xv[2][8];
#pragma unroll
  for (int ks = 0; ks < 2; ++ks) {
#pragma unroll
    for (int e = 0; e < 8; ++e) {
      int k = ks * 32 + lg * 8 + e;
      int kc2 = (k < 49) ? k : 0;
      int ka = (kc2 * 37) >> 8;
      int kb2 = kc2 - ka * 7;
      float x = vb[(size_t)((ka * 8 + wy) * 56 + (kb2 * 8 + wx)) * 16 + lr];
      xv[ks][e] = (k < 49) ? x : 0.f;
    }
  }

  // ---- md = max dii (kept in regs; mi stored AFTER cwf's last read) ----
  float md = fmaxf(fmaxf(diiv[0], diiv[1]), fmaxf(diiv[2], dii48));
#pragma unroll
  for (int o = 32; o >= 1; o >>= 1) md = fmaxf(md, __shfl_xor(md, o));
  asm volatile("s_waitcnt lgkmcnt(0)" ::: "memory");  // corr LDS writes retired (vmem in flight)

  // ---- build Sm fragments (hi/lo) from f32 cwf ----
  bf16x8 ah[4][2], al[4][2];
#pragma unroll
  for (int tt2 = 0; tt2 < 4; ++tt2) {
#pragma unroll
    for (int ks = 0; ks < 2; ++ks) {
      const int row = tt2 * 16 + lr;
      const int rowc = (row < 49) ? row : 0;
      const int cb = ks * 32 + lg * 8;
      f32x4 xa = *(const f32x4*)(cwf + rowc * 52 + cb);
      f32x4 xb = *(const f32x4*)(cwf + rowc * 52 + cb + 4);
      float xs[8] = {xa.x, xa.y, xa.z, xa.w, xb.x, xb.y, xb.z, xb.w};
      const bool rv = (row < 49);
#pragma unroll
      for (int e = 0; e < 8; ++e)
        if (!rv || (cb + e) >= 49) xs[e] = 0.f;
      union { u32x4 u; bf16x8 s; } Hh, Ll;
#pragma unroll
      for (int p = 0; p < 4; ++p) {
        unsigned short h0 = f2bf(xs[2*p]), h1 = f2bf(xs[2*p+1]);
        unsigned short l0 = f2bf(xs[2*p] - bf2f(h0)), l1 = f2bf(xs[2*p+1] - bf2f(h1));
        Hh.u[p] = (unsigned int)h0 | ((unsigned int)h1 << 16);
        Ll.u[p] = (unsigned int)l0 | ((unsigned int)l1 << 16);
      }
      ah[tt2][ks] = Hh.s;
      al[tt2][ks] = Ll.s;
    }
  }
  asm volatile("s_waitcnt lgkmcnt(0)" ::: "memory");  // cwf reads done; region reusable

  // ---- store mi into the dead-cwf tail (owners: c4==0 lanes; lane 0 row 48) ----
  if (c4 == 0) {
#pragma unroll
    for (int p = 0; p < 3; ++p) mi_s[p * 16 + ilg] = sqrtf(diiv[p] * md);
  }
  if (lane == 0) mi_s[48] = sqrtf(dii48 * md);

  // ---- Sm mfma + exp drain into Pb (aliases cwf rows 0..33, now dead) ----
#pragma unroll
  for (int rt = 0; rt < 4; ++rt) {
    f32x4 C[4];
#pragma unroll
    for (int ct = 0; ct < 4; ++ct) C[ct] = (f32x4)0.f;
#pragma unroll
    for (int ks = 0; ks < 2; ++ks) {
#pragma unroll
      for (int ct = 0; ct < 4; ++ct) {
        C[ct] = __builtin_amdgcn_mfma_f32_16x16x32_bf16(ah[rt][ks], ah[ct][ks], C[ct], 0, 0, 0);
        C[ct] = __builtin_amdgcn_mfma_f32_16x16x32_bf16(ah[rt][ks], al[ct][ks], C[ct], 0, 0, 0);
        C[ct] = __builtin_amdgcn_mfma_f32_16x16x32_bf16(al[rt][ks], ah[ct][ks], C[ct], 0, 0, 0);
      }
    }
    if (rt == 0) { asm volatile("s_waitcnt lgkmcnt(0)" ::: "memory"); }  // mi stores retired
#pragma unroll
    for (int reg = 0; reg < 4; ++reg) {
      int row = rt * 16 + lg * 4 + reg;
      float m = mi_s[(row < 49) ? row : 0];
#pragma unroll
      for (int ct = 0; ct < 4; ++ct) {
        float p = __expf(C[ct][reg] - m);
        if (row < 49) Pb[row * 72 + ct * 16 + lr] = f2bf(p);
      }
    }
  }
  asm volatile("" ::: "memory");  // Pb writes ordered before rowsum/PV reads

  // ---- motion row sums (over the bf16 values actually used) ----
  if (rowok) {
    const u32x4* pr = (const u32x4*)(Pb + il * 72);
    unsigned int uu[28];
#pragma unroll
    for (int w = 0; w < 7; ++w) *(u32x4*)&uu[4*w] = pr[w];
    float s = 0.f;
#pragma unroll
    for (int w = 0; w < 24; ++w)
      s += bf2f((unsigned short)(uu[w] & 0xffffu)) + bf2f((unsigned short)(uu[w] >> 16));
    s += bf2f((unsigned short)(uu[24] & 0xffffu));   // col 48
    scm[il] = 0.5f / s;
  }

  // ---- pack V fragments (hi/lo) from the hoisted raw loads ----
  bf16x8 vfh[2], vfl[2];
#pragma unroll
  for (int ks = 0; ks < 2; ++ks) {
    union { u32x4 u; bf16x8 s; } Hh, Ll;
#pragma unroll
    for (int p = 0; p < 4; ++p) {
      unsigned short h0 = f2bf(xv[ks][2*p]);
      unsigned short h1 = f2bf(xv[ks][2*p+1]);
      unsigned short l0 = f2bf(xv[ks][2*p]   - bf2f(h0));
      unsigned short l1 = f2bf(xv[ks][2*p+1] - bf2f(h1));
      Hh.u[p] = (unsigned int)h0 | ((unsigned int)h1 << 16);
      Ll.u[p] = (unsigned int)l0 | ((unsigned int)l1 << 16);
    }
    vfh[ks] = Hh.s;
    vfl[ks] = Ll.s;
  }

  // ---- motion PV ----
  f32x4 om[4];
#pragma unroll
  for (int rt = 0; rt < 4; ++rt) om[rt] = (f32x4)0.f;
#pragma unroll
  for (int ks = 0; ks < 2; ++ks) {
#pragma unroll
    for (int rt = 0; rt < 4; ++rt) {
      int row = rt * 16 + lr;
      int rowc = (row < 49) ? row : 0;
      bf16x8 pa = *(const bf16x8*)(Pb + rowc * 72 + ks * 32 + lg * 8);
      om[rt] = __builtin_amdgcn_mfma_f32_16x16x32_bf16(pa, vfh[ks], om[rt], 0, 0, 0);
      om[rt] = __builtin_amdgcn_mfma_f32_16x16x32_bf16(pa, vfl[ks], om[rt], 0, 0, 0);
    }
  }
  asm volatile("s_waitcnt lgkmcnt(0)" ::: "memory");  // motion Pb reads done before app overwrite

  // ---- appearance: qf fragments direct from global q + pos2 ----
  bf16x8 qf[4];
#pragma unroll
  for (int tt2 = 0; tt2 < 4; ++tt2) {
    int row = tt2 * 16 + lr;
    int rowc = (row < 49) ? row : 0;
    int a2 = (rowc * 37) >> 8;
    int b3 = rowc - a2 * 7;
    const int co = (lg & 1) * 8;        // channel offset (lanes lg>=2 masked to 0)
    const float* qsrc = qb + (size_t)((a2 * 8 + wy) * 56 + (b3 * 8 + wx)) * 16 + co;
    f32x4 qa = *(const f32x4*)qsrc;
    f32x4 qb4 = *(const f32x4*)(qsrc + 4);
    const float* p2 = pos2 + rowc * 16 + co;
    f32x4 pa = *(const f32x4*)p2;
    f32x4 pb4 = *(const f32x4*)(p2 + 4);
    f32x4 w0 = qa + pa, w1 = qb4 + pb4;
    float ws[8] = {w0.x, w0.y, w0.z, w0.w, w1.x, w1.y, w1.z, w1.w};
    const bool zv = (row >= 49) || (lg >= 2);
    union { u32x4 u; bf16x8 s; } Q;
#pragma unroll
    for (int p = 0; p < 4; ++p) {
      unsigned int v = (unsigned)f2bf(ws[2*p]) | ((unsigned)f2bf(ws[2*p+1]) << 16);
      Q.u[p] = zv ? 0u : v;
    }
    qf[tt2] = Q.s;
  }

  // ---- appearance gram (K=16, plain bf16, shift 0) + exp drain ----
#pragma unroll
  for (int rt = 0; rt < 4; ++rt) {
    f32x4 Ca[4];
#pragma unroll
    for (int ct = 0; ct < 4; ++ct) Ca[ct] = (f32x4)0.f;
#pragma unroll
    for (int ct = 0; ct < 4; ++ct)
      Ca[ct] = __builtin_amdgcn_mfma_f32_16x16x32_bf16(qf[rt], qf[ct], Ca[ct], 0, 0, 0);
#pragma unroll
    for (int reg = 0; reg < 4; ++reg) {
      int row = rt * 16 + lg * 4 + reg;
#pragma unroll
      for (int ct = 0; ct < 4; ++ct) {
        float p = __expf(Ca[ct][reg]);
        if (row < 49) Pb[row * 72 + ct * 16 + lr] = f2bf(p);
      }
    }
  }
  asm volatile("" ::: "memory");  // app Pb writes ordered before reads

  // ---- appearance row sums ----
  if (rowok) {
    const u32x4* pr = (const u32x4*)(Pb + il * 72);
    unsigned int uu[28];
#pragma unroll
    for (int w = 0; w < 7; ++w) *(u32x4*)&uu[4*w] = pr[w];
    float s = 0.f;
#pragma unroll
    for (int w = 0; w < 24; ++w)
      s += bf2f((unsigned short)(uu[w] & 0xffffu)) + bf2f((unsigned short)(uu[w] >> 16));
    s += bf2f((unsigned short)(uu[24] & 0xffffu));
    sca[il] = 0.5f / s;
  }

  // ---- appearance PV ----
  f32x4 oa[4];
#pragma unroll
  for (int rt = 0; rt < 4; ++rt) oa[rt] = (f32x4)0.f;
#pragma unroll
  for (int ks = 0; ks < 2; ++ks) {
#pragma unroll
    for (int rt = 0; rt < 4; ++rt) {
      int row = rt * 16 + lr;
      int rowc = (row < 49) ? row : 0;
      bf16x8 pa = *(const bf16x8*)(Pb + rowc * 72 + ks * 32 + lg * 8);
      oa[rt] = __builtin_amdgcn_mfma_f32_16x16x32_bf16(pa, vfh[ks], oa[rt], 0, 0, 0);
      oa[rt] = __builtin_amdgcn_mfma_f32_16x16x32_bf16(pa, vfl[ks], oa[rt], 0, 0, 0);
    }
  }

  // ---- epilogue: out = om*scm[row] + oa*sca[row], write (B,N,C) layout ----
  {
    int b = bt >> 6, e = (bt >> 3) & 7, tt = bt & 7;
    size_t obase = ((size_t)(b * NPIX + tt * HW_)) * 128 + e * 16 + lr;
#pragma unroll
    for (int rt = 0; rt < 4; ++rt) {
#pragma unroll
      for (int reg = 0; reg < 4; ++reg) {
        int row = rt * 16 + lg * 4 + reg;
        if (row < 49) {
          float o = om[rt][reg] * scm[row] + oa[rt][reg] * sca[row];
          int a2 = (row * 37) >> 8;
          int b3 = row - a2 * 7;
          mid[obase + (size_t)((a2 * 8 + wy) * 56 + (b3 * 8 + wx)) * 128] = o;
        }
      }
    }
  }
}

// ---------------------------------------------------------------------------
extern "C" void kernel_launch(void* const* d_in, const int* in_sizes, int n_in,
                              void* d_out, int out_size, void* d_ws, size_t ws_size,
                              hipStream_t stream) {
  (void)in_sizes; (void)n_in; (void)out_size; (void)ws_size;
  const float* x      = (const float*)d_in[0];
  const float* qkv_w  = (const float*)d_in[1];
  const float* proj_w = (const float*)d_in[2];
  const float* proj_b = (const float*)d_in[3];
  const float* pos1   = (const float*)d_in[4];
  const float* pos2   = (const float*)d_in[5];
  float* out = (float*)d_out;

  float* qn = (float*)d_ws;
  float* kc = qn + SLAB;
  float* vv = kc + SLAB;

  gemm128<0><<<dim3(392, 3), 256, 0, stream>>>(x, qkv_w, nullptr, qn, kc, vv, nullptr);
  attn_mfma<<<dim3(4096), 128, 0, stream>>>(qn, kc, vv, pos1, pos2, out);
  gemm128<1><<<dim3(392), 256, 0, stream>>>(out, proj_w, proj_b, nullptr, nullptr, nullptr, out);
}

// Round 11
// 266.423 us; speedup vs baseline: 1.1181x; 1.1181x over previous
//
#include <hip/hip_runtime.h>
#include <math.h>

// Problem constants (B=2, T=8, H=W=56, C=128, heads=8, hd=16, WS=7, nh=nw=8)
constexpr int H_   = 56;
constexpr int HW_  = 56 * 56;          // 3136
constexpr int NPIX = 8 * HW_;          // 25088 (per batch)
constexpr int SLAB = 128 * HW_ * 16;   // floats per q/k/v buffer

typedef __attribute__((ext_vector_type(8))) short bf16x8;
typedef __attribute__((ext_vector_type(4))) float f32x4;
typedef __attribute__((ext_vector_type(4))) unsigned int u32x4;

__device__ __forceinline__ unsigned short f2bf(float x) {
  unsigned int u = __float_as_uint(x);
  unsigned int r = (u + 0x7fffu + ((u >> 16) & 1u)) >> 16;
  return (unsigned short)r;
}
__device__ __forceinline__ float bf2f(unsigned short h) {
  return __uint_as_float(((unsigned int)h) << 16);
}
__device__ __forceinline__ int clamp55(int v) {
  return v < 0 ? 0 : (v > 55 ? 55 : v);
}

// ---------------------------------------------------------------------------
// GEMM: unchanged (K1 qkv+l2norm+scatter, K3 proj). ~52us combined.
// ---------------------------------------------------------------------------
template <int MODE>
__global__ __launch_bounds__(256, 3) void gemm128(
    const float* X, const float* __restrict__ Wt, const float* __restrict__ bias,
    float* __restrict__ Yq, float* __restrict__ Yk, float* __restrict__ Yv,
    float* Yout)
{
  __shared__ float xT[32][132];
  __shared__ float wT[32][132];
  const int tid = threadIdx.x;
  const int tx = tid & 15, ty = tid >> 4;
  const int mbase = blockIdx.x * 128;
  const int nt = (MODE == 0) ? (int)blockIdx.y : 0;
  const float* Wp = Wt + (size_t)nt * (128 * 128);

  float acc[8][8];
#pragma unroll
  for (int i = 0; i < 8; ++i)
#pragma unroll
    for (int j = 0; j < 8; ++j) acc[i][j] = 0.f;

  const int srow = tid >> 3;
  const int scol = (tid & 7) * 4;

  for (int kt = 0; kt < 4; ++kt) {
    if (kt) __syncthreads();
#pragma unroll
    for (int p = 0; p < 4; ++p) {
      int r = p * 32 + srow;
      float4 vx = *(const float4*)&X [(size_t)(mbase + r) * 128 + kt * 32 + scol];
      float4 vw = *(const float4*)&Wp[(size_t)r * 128 + kt * 32 + scol];
      xT[scol + 0][r] = vx.x; xT[scol + 1][r] = vx.y; xT[scol + 2][r] = vx.z; xT[scol + 3][r] = vx.w;
      wT[scol + 0][r] = vw.x; wT[scol + 1][r] = vw.y; wT[scol + 2][r] = vw.z; wT[scol + 3][r] = vw.w;
    }
    __syncthreads();
#pragma unroll 4
    for (int c = 0; c < 32; ++c) {
      float4 a0 = *(const float4*)&xT[c][tx * 4];
      float4 a1 = *(const float4*)&xT[c][64 + tx * 4];
      float4 b0 = *(const float4*)&wT[c][ty * 4];
      float4 b1 = *(const float4*)&wT[c][64 + ty * 4];
      float a[8] = {a0.x, a0.y, a0.z, a0.w, a1.x, a1.y, a1.z, a1.w};
      float b[8] = {b0.x, b0.y, b0.z, b0.w, b1.x, b1.y, b1.z, b1.w};
#pragma unroll
      for (int i = 0; i < 8; ++i)
#pragma unroll
        for (int j = 0; j < 8; ++j) acc[i][j] += a[i] * b[j];
    }
  }

  if (MODE == 0) {
    const int hq = ty >> 2;
    const int cq = (ty & 3) * 4;
    float* Ybase = (nt == 0) ? Yq : ((nt == 1) ? Yk : Yv);
#pragma unroll
    for (int i = 0; i < 8; ++i) {
      int gpix = mbase + ((i < 4) ? (tx * 4 + i) : (64 + tx * 4 + (i - 4)));
      int b = gpix / NPIX;
      int rem = gpix - b * NPIX;
      int t = rem / HW_;
      int s = rem - t * HW_;
      float s0 = acc[i][0]*acc[i][0] + acc[i][1]*acc[i][1] + acc[i][2]*acc[i][2] + acc[i][3]*acc[i][3];
      float s1 = acc[i][4]*acc[i][4] + acc[i][5]*acc[i][5] + acc[i][6]*acc[i][6] + acc[i][7]*acc[i][7];
      s0 += __shfl_xor(s0, 16); s0 += __shfl_xor(s0, 32);
      s1 += __shfl_xor(s1, 16); s1 += __shfl_xor(s1, 32);
      float r0 = 1.f, r1 = 1.f;
      if (nt < 2) {
        r0 = 1.f / fmaxf(sqrtf(s0), 1e-12f);
        r1 = 1.f / fmaxf(sqrtf(s1), 1e-12f);
      }
      int bt0 = (b * 8 + hq) * 8 + t;
      int bt1 = (b * 8 + hq + 4) * 8 + t;
      float* d0 = Ybase + ((size_t)bt0 * HW_ + s) * 16 + cq;
      float* d1 = Ybase + ((size_t)bt1 * HW_ + s) * 16 + cq;
      *(float4*)d0 = make_float4(acc[i][0]*r0, acc[i][1]*r0, acc[i][2]*r0, acc[i][3]*r0);
      *(float4*)d1 = make_float4(acc[i][4]*r1, acc[i][5]*r1, acc[i][6]*r1, acc[i][7]*r1);
    }
  } else {
    float4 bb0 = *(const float4*)&bias[ty * 4];
    float4 bb1 = *(const float4*)&bias[64 + ty * 4];
#pragma unroll
    for (int i = 0; i < 8; ++i) {
      int gpix = mbase + ((i < 4) ? (tx * 4 + i) : (64 + tx * 4 + (i - 4)));
      float* dst = Yout + (size_t)gpix * 128;
      *(float4*)&dst[ty * 4]      = make_float4(acc[i][0]+bb0.x, acc[i][1]+bb0.y, acc[i][2]+bb0.z, acc[i][3]+bb0.w);
      *(float4*)&dst[64 + ty * 4] = make_float4(acc[i][4]+bb1.x, acc[i][5]+bb1.y, acc[i][6]+bb1.z, acc[i][7]+bb1.w);
    }
  }
}

// ---------------------------------------------------------------------------
// MFMA window attention v9 = round-9 single-wave kernel with BATCHED scattered
// loads. Theory: R2 (VALU gram) did 360k VALU-cy/CU in 224us (67% busy); R9
// does 140k in 218us (27%) -> the MFMA version is stall-bound, and the only
// big stall source is the corr k-gather: compiler emits load->waitcnt->use
// per iteration (result reg feeds the dot), ~150 serialized L2 loads/wave.
// Fix: explicit register-array batches -- corr runs 6 fully-unrolled batches
// of 8 independent f32x4 loads (compile-time du/dv -> immediate offsets,
// clamped addr, value-masked OOB) then 8 dots; row-48 sweep batches 4 loads;
// qf build batches 2 tiles. ~18 waitcnt events/wave instead of ~150.
// All math / layout / phase structure identical to round 9.
// ---------------------------------------------------------------------------
__global__ __launch_bounds__(64, 3) void attn_mfma(
    const float* __restrict__ qn, const float* __restrict__ kn, const float* __restrict__ vv,
    const float* __restrict__ pos1, const float* __restrict__ pos2,
    float* __restrict__ mid)
{
  __shared__ __align__(16) unsigned char smem[10192];
  float*          cwf  = (float*)smem;                    // [49][52] f32 corr (phase 1)
  unsigned short* Pb   = (unsigned short*)smem;           // [49][72] bf16 (aliases cwf; 7056 B)
  float*          mi_s = (float*)(smem + 7104);           // [49] (dead-cwf tail)
  float*          scm  = (float*)(smem + 7304);           // [49]
  float*          sca  = (float*)(smem + 7504);           // [49]

  const int lane = threadIdx.x;
  const int lg = lane >> 4;       // mfma k-group
  const int lr = lane & 15;       // mfma row/col within tile
  const int c4  = lane & 3;       // corr: channel quarter
  const int ilg = lane >> 2;      // corr: row within pass / d within row-48 sweep
  // XCD-aware remap (8 XCDs, 8192 blocks, 1024 per XCD, 16 bt-groups each)
  const int bid = blockIdx.x;
  const int xcd = bid & 7;
  const int j = bid >> 3;                 // 0..1023
  const int bt = xcd * 16 + (j >> 6);     // bt-group pinned to one XCD
  const int win = j & 63;
  const int wy = win >> 3;
  const int wx = win & 7;
  const int t = bt & 7;
  const int btk = bt - t + ((t < 7) ? (t + 1) : 7);
  const float* qb = qn + (size_t)bt  * (HW_ * 16);
  const float* kb = kn + (size_t)btk * (HW_ * 16);
  const float* vb = vv + (size_t)bt  * (HW_ * 16);

  const bool rowok = (lane < 49);
  const int il = rowok ? lane : 48;

  // ---- P1: correlation, coalesced + load-batched. Passes p=0..2: rows 0..47.
  float diiv[3];
#pragma unroll
  for (int p = 0; p < 3; ++p) {
    const int il2 = p * 16 + ilg;            // 0..47
    const int ia2 = (il2 * 37) >> 8;         // il2/7
    const int ib2 = il2 - ia2 * 7;
    const int qh2 = ia2 * 8 + wy;
    const int qw2 = ib2 * 8 + wx;
    const f32x4 qv = *(const f32x4*)(qb + (size_t)(qh2 * 56 + qw2) * 16 + c4 * 4);
    float dii = 0.f;
    const float* p1r = pos1 + il2 * 49;
    float* cwr = cwf + il2 * 52;
#pragma unroll
    for (int dbase = 0; dbase < 48; dbase += 8) {
      f32x4 kv[8];
      // batch: 8 independent loads in flight (clamped addresses, in-slab)
#pragma unroll
      for (int e = 0; e < 8; ++e) {
        const int d = dbase + e;                 // compile-time
        const int du = d / 7, dv = d % 7;        // compile-time
        const int hc = clamp55(qh2 + du - 3);
        const int wc = clamp55(qw2 + dv - 3);
        kv[e] = *(const f32x4*)(kb + (size_t)(hc * 56 + wc) * 16 + c4 * 4);
      }
      // consume: dots + masks + shfl reduce + LDS write
#pragma unroll
      for (int e = 0; e < 8; ++e) {
        const int d = dbase + e;
        const int du = d / 7, dv = d % 7;
        const int hh = qh2 + du - 3, ww = qw2 + dv - 3;
        float pd = fmaf(qv.x, kv[e].x, fmaf(qv.y, kv[e].y, fmaf(qv.z, kv[e].z, qv.w * kv[e].w)));
        pd = ((unsigned)hh < 56u && (unsigned)ww < 56u) ? pd : 0.f;
        pd += __shfl_xor(pd, 1);
        pd += __shfl_xor(pd, 2);
        const float val = pd + p1r[d];
        dii += val * val;
        if (c4 == 0) cwr[d] = val;
      }
    }
    { // d = 48 tail (du=6, dv=6)
      const int hh = qh2 + 3, ww = qw2 + 3;
      float pd = 0.f;
      if ((unsigned)hh < 56u && (unsigned)ww < 56u) {
        const f32x4 kv = *(const f32x4*)(kb + (size_t)(hh * 56 + ww) * 16 + c4 * 4);
        pd = fmaf(qv.x, kv.x, fmaf(qv.y, kv.y, fmaf(qv.z, kv.z, qv.w * kv.w)));
      }
      pd += __shfl_xor(pd, 1);
      pd += __shfl_xor(pd, 2);
      const float val = pd + p1r[48];
      dii += val * val;
      if (c4 == 0) cwr[48] = val;
    }
    diiv[p] = dii;
  }

  // ---- row 48 sweep: lanes = (c4, d-group); 4 loads batched ----
  float dii48;
  {
    const int qh2 = 48 + wy, qw2 = 48 + wx;
    const f32x4 qv = *(const f32x4*)(qb + (size_t)(qh2 * 56 + qw2) * 16 + c4 * 4);
    f32x4 kv4[4];
#pragma unroll
    for (int dp = 0; dp < 4; ++dp) {
      const int d = dp * 16 + ilg;
      const int dc = (d < 49) ? d : 0;
      const int du = (dc * 37) >> 8, dv = dc - du * 7;
      const int hc = clamp55(qh2 + du - 3);
      const int wc = clamp55(qw2 + dv - 3);
      kv4[dp] = *(const f32x4*)(kb + (size_t)(hc * 56 + wc) * 16 + c4 * 4);
    }
    float dacc = 0.f;
#pragma unroll
    for (int dp = 0; dp < 4; ++dp) {
      const int d = dp * 16 + ilg;
      const bool dok = (d < 49);
      const int dc = dok ? d : 0;
      const int du = (dc * 37) >> 8, dv = dc - du * 7;
      const int hh = qh2 + du - 3, ww = qw2 + dv - 3;
      float pd = fmaf(qv.x, kv4[dp].x, fmaf(qv.y, kv4[dp].y, fmaf(qv.z, kv4[dp].z, qv.w * kv4[dp].w)));
      pd = (dok && (unsigned)hh < 56u && (unsigned)ww < 56u) ? pd : 0.f;
      pd += __shfl_xor(pd, 1);
      pd += __shfl_xor(pd, 2);
      if (dok) {
        const float val = pd + pos1[48 * 49 + dc];
        dacc += val * val;
        if (c4 == 0) cwf[48 * 52 + dc] = val;
      }
    }
    dacc += __shfl_xor(dacc, 4);
    dacc += __shfl_xor(dacc, 8);
    dacc += __shfl_xor(dacc, 16);
    dacc += __shfl_xor(dacc, 32);
    dii48 = dacc;
  }

  // ---- issue V loads NOW (raw f32, packed after Sm phase) ----
  float xv[2][8];
#pragma unroll
  for (int ks = 0; ks < 2; ++ks) {
#pragma unroll
    for (int e = 0; e < 8; ++e) {
      int k = ks * 32 + lg * 8 + e;
      int kc2 = (k < 49) ? k : 0;
      int ka = (kc2 * 37) >> 8;
      int kb2 = kc2 - ka * 7;
      float x = vb[(size_t)((ka * 8 + wy) * 56 + (kb2 * 8 + wx)) * 16 + lr];
      xv[ks][e] = (k < 49) ? x : 0.f;
    }
  }

  // ---- md = max dii (kept in regs; mi stored AFTER cwf's last read) ----
  float md = fmaxf(fmaxf(diiv[0], diiv[1]), fmaxf(diiv[2], dii48));
#pragma unroll
  for (int o = 32; o >= 1; o >>= 1) md = fmaxf(md, __shfl_xor(md, o));
  asm volatile("s_waitcnt lgkmcnt(0)" ::: "memory");  // corr LDS writes retired (vmem in flight)

  // ---- build Sm fragments (hi/lo) from f32 cwf ----
  bf16x8 ah[4][2], al[4][2];
#pragma unroll
  for (int tt2 = 0; tt2 < 4; ++tt2) {
#pragma unroll
    for (int ks = 0; ks < 2; ++ks) {
      const int row = tt2 * 16 + lr;
      const int rowc = (row < 49) ? row : 0;
      const int cb = ks * 32 + lg * 8;
      f32x4 xa = *(const f32x4*)(cwf + rowc * 52 + cb);
      f32x4 xb = *(const f32x4*)(cwf + rowc * 52 + cb + 4);
      float xs[8] = {xa.x, xa.y, xa.z, xa.w, xb.x, xb.y, xb.z, xb.w};
      const bool rv = (row < 49);
#pragma unroll
      for (int e = 0; e < 8; ++e)
        if (!rv || (cb + e) >= 49) xs[e] = 0.f;
      union { u32x4 u; bf16x8 s; } Hh, Ll;
#pragma unroll
      for (int p = 0; p < 4; ++p) {
        unsigned short h0 = f2bf(xs[2*p]), h1 = f2bf(xs[2*p+1]);
        unsigned short l0 = f2bf(xs[2*p] - bf2f(h0)), l1 = f2bf(xs[2*p+1] - bf2f(h1));
        Hh.u[p] = (unsigned int)h0 | ((unsigned int)h1 << 16);
        Ll.u[p] = (unsigned int)l0 | ((unsigned int)l1 << 16);
      }
      ah[tt2][ks] = Hh.s;
      al[tt2][ks] = Ll.s;
    }
  }
  asm volatile("s_waitcnt lgkmcnt(0)" ::: "memory");  // cwf reads done; region reusable

  // ---- store mi into the dead-cwf tail ----
  if (c4 == 0) {
#pragma unroll
    for (int p = 0; p < 3; ++p) mi_s[p * 16 + ilg] = sqrtf(diiv[p] * md);
  }
  if (lane == 0) mi_s[48] = sqrtf(dii48 * md);

  // ---- Sm mfma + exp drain into Pb (aliases cwf, now dead) ----
#pragma unroll
  for (int rt = 0; rt < 4; ++rt) {
    f32x4 C[4];
#pragma unroll
    for (int ct = 0; ct < 4; ++ct) C[ct] = (f32x4)0.f;
#pragma unroll
    for (int ks = 0; ks < 2; ++ks) {
#pragma unroll
      for (int ct = 0; ct < 4; ++ct) {
        C[ct] = __builtin_amdgcn_mfma_f32_16x16x32_bf16(ah[rt][ks], ah[ct][ks], C[ct], 0, 0, 0);
        C[ct] = __builtin_amdgcn_mfma_f32_16x16x32_bf16(ah[rt][ks], al[ct][ks], C[ct], 0, 0, 0);
        C[ct] = __builtin_amdgcn_mfma_f32_16x16x32_bf16(al[rt][ks], ah[ct][ks], C[ct], 0, 0, 0);
      }
    }
    if (rt == 0) { asm volatile("s_waitcnt lgkmcnt(0)" ::: "memory"); }  // mi stores retired
#pragma unroll
    for (int reg = 0; reg < 4; ++reg) {
      int row = rt * 16 + lg * 4 + reg;
      float m = mi_s[(row < 49) ? row : 0];
#pragma unroll
      for (int ct = 0; ct < 4; ++ct) {
        float p = __expf(C[ct][reg] - m);
        if (row < 49) Pb[row * 72 + ct * 16 + lr] = f2bf(p);
      }
    }
  }
  asm volatile("" ::: "memory");  // Pb writes ordered before rowsum/PV reads

  // ---- motion row sums (over the bf16 values actually used) ----
  if (rowok) {
    const u32x4* pr = (const u32x4*)(Pb + il * 72);
    unsigned int uu[28];
#pragma unroll
    for (int w = 0; w < 7; ++w) *(u32x4*)&uu[4*w] = pr[w];
    float s = 0.f;
#pragma unroll
    for (int w = 0; w < 24; ++w)
      s += bf2f((unsigned short)(uu[w] & 0xffffu)) + bf2f((unsigned short)(uu[w] >> 16));
    s += bf2f((unsigned short)(uu[24] & 0xffffu));   // col 48
    scm[il] = 0.5f / s;
  }

  // ---- pack V fragments (hi/lo) from the hoisted raw loads ----
  bf16x8 vfh[2], vfl[2];
#pragma unroll
  for (int ks = 0; ks < 2; ++ks) {
    union { u32x4 u; bf16x8 s; } Hh, Ll;
#pragma unroll
    for (int p = 0; p < 4; ++p) {
      unsigned short h0 = f2bf(xv[ks][2*p]);
      unsigned short h1 = f2bf(xv[ks][2*p+1]);
      unsigned short l0 = f2bf(xv[ks][2*p]   - bf2f(h0));
      unsigned short l1 = f2bf(xv[ks][2*p+1] - bf2f(h1));
      Hh.u[p] = (unsigned int)h0 | ((unsigned int)h1 << 16);
      Ll.u[p] = (unsigned int)l0 | ((unsigned int)l1 << 16);
    }
    vfh[ks] = Hh.s;
    vfl[ks] = Ll.s;
  }

  // ---- motion PV ----
  f32x4 om[4];
#pragma unroll
  for (int rt = 0; rt < 4; ++rt) om[rt] = (f32x4)0.f;
#pragma unroll
  for (int ks = 0; ks < 2; ++ks) {
#pragma unroll
    for (int rt = 0; rt < 4; ++rt) {
      int row = rt * 16 + lr;
      int rowc = (row < 49) ? row : 0;
      bf16x8 pa = *(const bf16x8*)(Pb + rowc * 72 + ks * 32 + lg * 8);
      om[rt] = __builtin_amdgcn_mfma_f32_16x16x32_bf16(pa, vfh[ks], om[rt], 0, 0, 0);
      om[rt] = __builtin_amdgcn_mfma_f32_16x16x32_bf16(pa, vfl[ks], om[rt], 0, 0, 0);
    }
  }
  asm volatile("s_waitcnt lgkmcnt(0)" ::: "memory");  // motion Pb reads done before app overwrite

  // ---- appearance: qf fragments direct from global q + pos2 (batched 2 tiles) ----
  bf16x8 qf[4];
#pragma unroll
  for (int half = 0; half < 2; ++half) {
    f32x4 qa_[2], qb_[2], pa_[2], pb_[2];
#pragma unroll
    for (int u = 0; u < 2; ++u) {
      const int tt2 = half * 2 + u;
      int row = tt2 * 16 + lr;
      int rowc = (row < 49) ? row : 0;
      int a2 = (rowc * 37) >> 8;
      int b3 = rowc - a2 * 7;
      const int co = (lg & 1) * 8;
      const float* qsrc = qb + (size_t)((a2 * 8 + wy) * 56 + (b3 * 8 + wx)) * 16 + co;
      qa_[u] = *(const f32x4*)qsrc;
      qb_[u] = *(const f32x4*)(qsrc + 4);
      const float* p2 = pos2 + rowc * 16 + co;
      pa_[u] = *(const f32x4*)p2;
      pb_[u] = *(const f32x4*)(p2 + 4);
    }
#pragma unroll
    for (int u = 0; u < 2; ++u) {
      const int tt2 = half * 2 + u;
      int row = tt2 * 16 + lr;
      f32x4 w0 = qa_[u] + pa_[u], w1 = qb_[u] + pb_[u];
      float ws[8] = {w0.x, w0.y, w0.z, w0.w, w1.x, w1.y, w1.z, w1.w};
      const bool zv = (row >= 49) || (lg >= 2);
      union { u32x4 u4; bf16x8 s; } Q;
#pragma unroll
      for (int p = 0; p < 4; ++p) {
        unsigned int v = (unsigned)f2bf(ws[2*p]) | ((unsigned)f2bf(ws[2*p+1]) << 16);
        Q.u4[p] = zv ? 0u : v;
      }
      qf[tt2] = Q.s;
    }
  }

  // ---- appearance gram (K=16, plain bf16, shift 0) + exp drain ----
#pragma unroll
  for (int rt = 0; rt < 4; ++rt) {
    f32x4 Ca[4];
#pragma unroll
    for (int ct = 0; ct < 4; ++ct) Ca[ct] = (f32x4)0.f;
#pragma unroll
    for (int ct = 0; ct < 4; ++ct)
      Ca[ct] = __builtin_amdgcn_mfma_f32_16x16x32_bf16(qf[rt], qf[ct], Ca[ct], 0, 0, 0);
#pragma unroll
    for (int reg = 0; reg < 4; ++reg) {
      int row = rt * 16 + lg * 4 + reg;
#pragma unroll
      for (int ct = 0; ct < 4; ++ct) {
        float p = __expf(Ca[ct][reg]);
        if (row < 49) Pb[row * 72 + ct * 16 + lr] = f2bf(p);
      }
    }
  }
  asm volatile("" ::: "memory");  // app Pb writes ordered before reads

  // ---- appearance row sums ----
  if (rowok) {
    const u32x4* pr = (const u32x4*)(Pb + il * 72);
    unsigned int uu[28];
#pragma unroll
    for (int w = 0; w < 7; ++w) *(u32x4*)&uu[4*w] = pr[w];
    float s = 0.f;
#pragma unroll
    for (int w = 0; w < 24; ++w)
      s += bf2f((unsigned short)(uu[w] & 0xffffu)) + bf2f((unsigned short)(uu[w] >> 16));
    s += bf2f((unsigned short)(uu[24] & 0xffffu));
    sca[il] = 0.5f / s;
  }

  // ---- appearance PV ----
  f32x4 oa[4];
#pragma unroll
  for (int rt = 0; rt < 4; ++rt) oa[rt] = (f32x4)0.f;
#pragma unroll
  for (int ks = 0; ks < 2; ++ks) {
#pragma unroll
    for (int rt = 0; rt < 4; ++rt) {
      int row = rt * 16 + lr;
      int rowc = (row < 49) ? row : 0;
      bf16x8 pa = *(const bf16x8*)(Pb + rowc * 72 + ks * 32 + lg * 8);
      oa[rt] = __builtin_amdgcn_mfma_f32_16x16x32_bf16(pa, vfh[ks], oa[rt], 0, 0, 0);
      oa[rt] = __builtin_amdgcn_mfma_f32_16x16x32_bf16(pa, vfl[ks], oa[rt], 0, 0, 0);
    }
  }

  // ---- epilogue: out = om*scm[row] + oa*sca[row], write (B,N,C) layout ----
  {
    int b = bt >> 6, e = (bt >> 3) & 7, tt = bt & 7;
    size_t obase = ((size_t)(b * NPIX + tt * HW_)) * 128 + e * 16 + lr;
#pragma unroll
    for (int rt = 0; rt < 4; ++rt) {
#pragma unroll
      for (int reg = 0; reg < 4; ++reg) {
        int row = rt * 16 + lg * 4 + reg;
        if (row < 49) {
          float o = om[rt][reg] * scm[row] + oa[rt][reg] * sca[row];
          int a2 = (row * 37) >> 8;
          int b3 = row - a2 * 7;
          mid[obase + (size_t)((a2 * 8 + wy) * 56 + (b3 * 8 + wx)) * 128] = o;
        }
      }
    }
  }
}

// ---------------------------------------------------------------------------
extern "C" void kernel_launch(void* const* d_in, const int* in_sizes, int n_in,
                              void* d_out, int out_size, void* d_ws, size_t ws_size,
                              hipStream_t stream) {
  (void)in_sizes; (void)n_in; (void)out_size; (void)ws_size;
  const float* x      = (const float*)d_in[0];
  const float* qkv_w  = (const float*)d_in[1];
  const float* proj_w = (const float*)d_in[2];
  const float* proj_b = (const float*)d_in[3];
  const float* pos1   = (const float*)d_in[4];
  const float* pos2   = (const float*)d_in[5];
  float* out = (float*)d_out;

  float* qn = (float*)d_ws;
  float* kc = qn + SLAB;
  float* vv = kc + SLAB;

  gemm128<0><<<dim3(392, 3), 256, 0, stream>>>(x, qkv_w, nullptr, qn, kc, vv, nullptr);
  attn_mfma<<<dim3(8192), 64, 0, stream>>>(qn, kc, vv, pos1, pos2, out);
  gemm128<1><<<dim3(392), 256, 0, stream>>>(out, proj_w, proj_b, nullptr, nullptr, nullptr, out);
}

// Round 12
// 248.139 us; speedup vs baseline: 1.2005x; 1.0737x over previous
//
#include <hip/hip_runtime.h>
#include <math.h>

// Problem constants (B=2, T=8, H=W=56, C=128, heads=8, hd=16, WS=7, nh=nw=8)
constexpr int H_   = 56;
constexpr int HW_  = 56 * 56;          // 3136
constexpr int NPIX = 8 * HW_;          // 25088 (per batch)
constexpr int SLAB = 128 * HW_ * 16;   // floats per q/k/v buffer

typedef __attribute__((ext_vector_type(8))) short bf16x8;
typedef __attribute__((ext_vector_type(4))) float f32x4;
typedef __attribute__((ext_vector_type(4))) unsigned int u32x4;

__device__ __forceinline__ unsigned short f2bf(float x) {
  unsigned int u = __float_as_uint(x);
  unsigned int r = (u + 0x7fffu + ((u >> 16) & 1u)) >> 16;
  return (unsigned short)r;
}
__device__ __forceinline__ float bf2f(unsigned short h) {
  return __uint_as_float(((unsigned int)h) << 16);
}
__device__ __forceinline__ int clamp55(int v) {
  return v < 0 ? 0 : (v > 55 ? 55 : v);
}

// ---------------------------------------------------------------------------
// GEMM: unchanged (K1 qkv+l2norm+scatter, K3 proj). ~45us combined.
// ---------------------------------------------------------------------------
template <int MODE>
__global__ __launch_bounds__(256, 3) void gemm128(
    const float* X, const float* __restrict__ Wt, const float* __restrict__ bias,
    float* __restrict__ Yq, float* __restrict__ Yk, float* __restrict__ Yv,
    float* Yout)
{
  __shared__ float xT[32][132];
  __shared__ float wT[32][132];
  const int tid = threadIdx.x;
  const int tx = tid & 15, ty = tid >> 4;
  const int mbase = blockIdx.x * 128;
  const int nt = (MODE == 0) ? (int)blockIdx.y : 0;
  const float* Wp = Wt + (size_t)nt * (128 * 128);

  float acc[8][8];
#pragma unroll
  for (int i = 0; i < 8; ++i)
#pragma unroll
    for (int j = 0; j < 8; ++j) acc[i][j] = 0.f;

  const int srow = tid >> 3;
  const int scol = (tid & 7) * 4;

  for (int kt = 0; kt < 4; ++kt) {
    if (kt) __syncthreads();
#pragma unroll
    for (int p = 0; p < 4; ++p) {
      int r = p * 32 + srow;
      float4 vx = *(const float4*)&X [(size_t)(mbase + r) * 128 + kt * 32 + scol];
      float4 vw = *(const float4*)&Wp[(size_t)r * 128 + kt * 32 + scol];
      xT[scol + 0][r] = vx.x; xT[scol + 1][r] = vx.y; xT[scol + 2][r] = vx.z; xT[scol + 3][r] = vx.w;
      wT[scol + 0][r] = vw.x; wT[scol + 1][r] = vw.y; wT[scol + 2][r] = vw.z; wT[scol + 3][r] = vw.w;
    }
    __syncthreads();
#pragma unroll 4
    for (int c = 0; c < 32; ++c) {
      float4 a0 = *(const float4*)&xT[c][tx * 4];
      float4 a1 = *(const float4*)&xT[c][64 + tx * 4];
      float4 b0 = *(const float4*)&wT[c][ty * 4];
      float4 b1 = *(const float4*)&wT[c][64 + ty * 4];
      float a[8] = {a0.x, a0.y, a0.z, a0.w, a1.x, a1.y, a1.z, a1.w};
      float b[8] = {b0.x, b0.y, b0.z, b0.w, b1.x, b1.y, b1.z, b1.w};
#pragma unroll
      for (int i = 0; i < 8; ++i)
#pragma unroll
        for (int j = 0; j < 8; ++j) acc[i][j] += a[i] * b[j];
    }
  }

  if (MODE == 0) {
    const int hq = ty >> 2;
    const int cq = (ty & 3) * 4;
    float* Ybase = (nt == 0) ? Yq : ((nt == 1) ? Yk : Yv);
#pragma unroll
    for (int i = 0; i < 8; ++i) {
      int gpix = mbase + ((i < 4) ? (tx * 4 + i) : (64 + tx * 4 + (i - 4)));
      int b = gpix / NPIX;
      int rem = gpix - b * NPIX;
      int t = rem / HW_;
      int s = rem - t * HW_;
      float s0 = acc[i][0]*acc[i][0] + acc[i][1]*acc[i][1] + acc[i][2]*acc[i][2] + acc[i][3]*acc[i][3];
      float s1 = acc[i][4]*acc[i][4] + acc[i][5]*acc[i][5] + acc[i][6]*acc[i][6] + acc[i][7]*acc[i][7];
      s0 += __shfl_xor(s0, 16); s0 += __shfl_xor(s0, 32);
      s1 += __shfl_xor(s1, 16); s1 += __shfl_xor(s1, 32);
      float r0 = 1.f, r1 = 1.f;
      if (nt < 2) {
        r0 = 1.f / fmaxf(sqrtf(s0), 1e-12f);
        r1 = 1.f / fmaxf(sqrtf(s1), 1e-12f);
      }
      int bt0 = (b * 8 + hq) * 8 + t;
      int bt1 = (b * 8 + hq + 4) * 8 + t;
      float* d0 = Ybase + ((size_t)bt0 * HW_ + s) * 16 + cq;
      float* d1 = Ybase + ((size_t)bt1 * HW_ + s) * 16 + cq;
      *(float4*)d0 = make_float4(acc[i][0]*r0, acc[i][1]*r0, acc[i][2]*r0, acc[i][3]*r0);
      *(float4*)d1 = make_float4(acc[i][4]*r1, acc[i][5]*r1, acc[i][6]*r1, acc[i][7]*r1);
    }
  } else {
    float4 bb0 = *(const float4*)&bias[ty * 4];
    float4 bb1 = *(const float4*)&bias[64 + ty * 4];
#pragma unroll
    for (int i = 0; i < 8; ++i) {
      int gpix = mbase + ((i < 4) ? (tx * 4 + i) : (64 + tx * 4 + (i - 4)));
      float* dst = Yout + (size_t)gpix * 128;
      *(float4*)&dst[ty * 4]      = make_float4(acc[i][0]+bb0.x, acc[i][1]+bb0.y, acc[i][2]+bb0.z, acc[i][3]+bb0.w);
      *(float4*)&dst[64 + ty * 4] = make_float4(acc[i][4]+bb1.x, acc[i][5]+bb1.y, acc[i][6]+bb1.z, acc[i][7]+bb1.w);
    }
  }
}

// ---------------------------------------------------------------------------
// MFMA window attention v10 = round-11 batched-load body with
// __launch_bounds__(64, 2). Round 11's batch test was INVALID: at (64,3)
// (~170 unified-reg cap) the allocator spilled the kv[8] batch arrays to
// scratch (WRITE_SIZE 31->84MB, VGPR pinned 84) instead of allocating 32
// more VGPRs -- same unified VGPR/AGPR pathology as rounds 6-8. (64,2)
// (cap ~256, loose minimum) lets the batch live in registers: ~8 loads in
// flight per corr batch instead of 1-2. Validity check: WRITE back to ~25MB.
// All math / layout / phase structure identical to rounds 9/11.
// ---------------------------------------------------------------------------
__global__ __launch_bounds__(64, 2) void attn_mfma(
    const float* __restrict__ qn, const float* __restrict__ kn, const float* __restrict__ vv,
    const float* __restrict__ pos1, const float* __restrict__ pos2,
    float* __restrict__ mid)
{
  __shared__ __align__(16) unsigned char smem[10192];
  float*          cwf  = (float*)smem;                    // [49][52] f32 corr (phase 1)
  unsigned short* Pb   = (unsigned short*)smem;           // [49][72] bf16 (aliases cwf; 7056 B)
  float*          mi_s = (float*)(smem + 7104);           // [49] (dead-cwf tail)
  float*          scm  = (float*)(smem + 7304);           // [49]
  float*          sca  = (float*)(smem + 7504);           // [49]

  const int lane = threadIdx.x;
  const int lg = lane >> 4;       // mfma k-group
  const int lr = lane & 15;       // mfma row/col within tile
  const int c4  = lane & 3;       // corr: channel quarter
  const int ilg = lane >> 2;      // corr: row within pass / d within row-48 sweep
  // XCD-aware remap (8 XCDs, 8192 blocks, 1024 per XCD, 16 bt-groups each)
  const int bid = blockIdx.x;
  const int xcd = bid & 7;
  const int j = bid >> 3;                 // 0..1023
  const int bt = xcd * 16 + (j >> 6);     // bt-group pinned to one XCD
  const int win = j & 63;
  const int wy = win >> 3;
  const int wx = win & 7;
  const int t = bt & 7;
  const int btk = bt - t + ((t < 7) ? (t + 1) : 7);
  const float* qb = qn + (size_t)bt  * (HW_ * 16);
  const float* kb = kn + (size_t)btk * (HW_ * 16);
  const float* vb = vv + (size_t)bt  * (HW_ * 16);

  const bool rowok = (lane < 49);
  const int il = rowok ? lane : 48;

  // ---- P1: correlation, coalesced + load-batched. Passes p=0..2: rows 0..47.
  float diiv[3];
#pragma unroll
  for (int p = 0; p < 3; ++p) {
    const int il2 = p * 16 + ilg;            // 0..47
    const int ia2 = (il2 * 37) >> 8;         // il2/7
    const int ib2 = il2 - ia2 * 7;
    const int qh2 = ia2 * 8 + wy;
    const int qw2 = ib2 * 8 + wx;
    const f32x4 qv = *(const f32x4*)(qb + (size_t)(qh2 * 56 + qw2) * 16 + c4 * 4);
    float dii = 0.f;
    const float* p1r = pos1 + il2 * 49;
    float* cwr = cwf + il2 * 52;
#pragma unroll
    for (int dbase = 0; dbase < 48; dbase += 8) {
      f32x4 kv[8];
      // batch: 8 independent loads in flight (clamped addresses, in-slab)
#pragma unroll
      for (int e = 0; e < 8; ++e) {
        const int d = dbase + e;                 // compile-time
        const int du = d / 7, dv = d % 7;        // compile-time
        const int hc = clamp55(qh2 + du - 3);
        const int wc = clamp55(qw2 + dv - 3);
        kv[e] = *(const f32x4*)(kb + (size_t)(hc * 56 + wc) * 16 + c4 * 4);
      }
      // consume: dots + masks + shfl reduce + LDS write
#pragma unroll
      for (int e = 0; e < 8; ++e) {
        const int d = dbase + e;
        const int du = d / 7, dv = d % 7;
        const int hh = qh2 + du - 3, ww = qw2 + dv - 3;
        float pd = fmaf(qv.x, kv[e].x, fmaf(qv.y, kv[e].y, fmaf(qv.z, kv[e].z, qv.w * kv[e].w)));
        pd = ((unsigned)hh < 56u && (unsigned)ww < 56u) ? pd : 0.f;
        pd += __shfl_xor(pd, 1);
        pd += __shfl_xor(pd, 2);
        const float val = pd + p1r[d];
        dii += val * val;
        if (c4 == 0) cwr[d] = val;
      }
    }
    { // d = 48 tail (du=6, dv=6)
      const int hh = qh2 + 3, ww = qw2 + 3;
      float pd = 0.f;
      if ((unsigned)hh < 56u && (unsigned)ww < 56u) {
        const f32x4 kv = *(const f32x4*)(kb + (size_t)(hh * 56 + ww) * 16 + c4 * 4);
        pd = fmaf(qv.x, kv.x, fmaf(qv.y, kv.y, fmaf(qv.z, kv.z, qv.w * kv.w)));
      }
      pd += __shfl_xor(pd, 1);
      pd += __shfl_xor(pd, 2);
      const float val = pd + p1r[48];
      dii += val * val;
      if (c4 == 0) cwr[48] = val;
    }
    diiv[p] = dii;
  }

  // ---- row 48 sweep: lanes = (c4, d-group); 4 loads batched ----
  float dii48;
  {
    const int qh2 = 48 + wy, qw2 = 48 + wx;
    const f32x4 qv = *(const f32x4*)(qb + (size_t)(qh2 * 56 + qw2) * 16 + c4 * 4);
    f32x4 kv4[4];
#pragma unroll
    for (int dp = 0; dp < 4; ++dp) {
      const int d = dp * 16 + ilg;
      const int dc = (d < 49) ? d : 0;
      const int du = (dc * 37) >> 8, dv = dc - du * 7;
      const int hc = clamp55(qh2 + du - 3);
      const int wc = clamp55(qw2 + dv - 3);
      kv4[dp] = *(const f32x4*)(kb + (size_t)(hc * 56 + wc) * 16 + c4 * 4);
    }
    float dacc = 0.f;
#pragma unroll
    for (int dp = 0; dp < 4; ++dp) {
      const int d = dp * 16 + ilg;
      const bool dok = (d < 49);
      const int dc = dok ? d : 0;
      const int du = (dc * 37) >> 8, dv = dc - du * 7;
      const int hh = qh2 + du - 3, ww = qw2 + dv - 3;
      float pd = fmaf(qv.x, kv4[dp].x, fmaf(qv.y, kv4[dp].y, fmaf(qv.z, kv4[dp].z, qv.w * kv4[dp].w)));
      pd = (dok && (unsigned)hh < 56u && (unsigned)ww < 56u) ? pd : 0.f;
      pd += __shfl_xor(pd, 1);
      pd += __shfl_xor(pd, 2);
      if (dok) {
        const float val = pd + pos1[48 * 49 + dc];
        dacc += val * val;
        if (c4 == 0) cwf[48 * 52 + dc] = val;
      }
    }
    dacc += __shfl_xor(dacc, 4);
    dacc += __shfl_xor(dacc, 8);
    dacc += __shfl_xor(dacc, 16);
    dacc += __shfl_xor(dacc, 32);
    dii48 = dacc;
  }

  // ---- issue V loads NOW (raw f32, packed after Sm phase) ----
  float xv[2][8];
#pragma unroll
  for (int ks = 0; ks < 2; ++ks) {
#pragma unroll
    for (int e = 0; e < 8; ++e) {
      int k = ks * 32 + lg * 8 + e;
      int kc2 = (k < 49) ? k : 0;
      int ka = (kc2 * 37) >> 8;
      int kb2 = kc2 - ka * 7;
      float x = vb[(size_t)((ka * 8 + wy) * 56 + (kb2 * 8 + wx)) * 16 + lr];
      xv[ks][e] = (k < 49) ? x : 0.f;
    }
  }

  // ---- md = max dii (kept in regs; mi stored AFTER cwf's last read) ----
  float md = fmaxf(fmaxf(diiv[0], diiv[1]), fmaxf(diiv[2], dii48));
#pragma unroll
  for (int o = 32; o >= 1; o >>= 1) md = fmaxf(md, __shfl_xor(md, o));
  asm volatile("s_waitcnt lgkmcnt(0)" ::: "memory");  // corr LDS writes retired (vmem in flight)

  // ---- build Sm fragments (hi/lo) from f32 cwf ----
  bf16x8 ah[4][2], al[4][2];
#pragma unroll
  for (int tt2 = 0; tt2 < 4; ++tt2) {
#pragma unroll
    for (int ks = 0; ks < 2; ++ks) {
      const int row = tt2 * 16 + lr;
      const int rowc = (row < 49) ? row : 0;
      const int cb = ks * 32 + lg * 8;
      f32x4 xa = *(const f32x4*)(cwf + rowc * 52 + cb);
      f32x4 xb = *(const f32x4*)(cwf + rowc * 52 + cb + 4);
      float xs[8] = {xa.x, xa.y, xa.z, xa.w, xb.x, xb.y, xb.z, xb.w};
      const bool rv = (row < 49);
#pragma unroll
      for (int e = 0; e < 8; ++e)
        if (!rv || (cb + e) >= 49) xs[e] = 0.f;
      union { u32x4 u; bf16x8 s; } Hh, Ll;
#pragma unroll
      for (int p = 0; p < 4; ++p) {
        unsigned short h0 = f2bf(xs[2*p]), h1 = f2bf(xs[2*p+1]);
        unsigned short l0 = f2bf(xs[2*p] - bf2f(h0)), l1 = f2bf(xs[2*p+1] - bf2f(h1));
        Hh.u[p] = (unsigned int)h0 | ((unsigned int)h1 << 16);
        Ll.u[p] = (unsigned int)l0 | ((unsigned int)l1 << 16);
      }
      ah[tt2][ks] = Hh.s;
      al[tt2][ks] = Ll.s;
    }
  }
  asm volatile("s_waitcnt lgkmcnt(0)" ::: "memory");  // cwf reads done; region reusable

  // ---- store mi into the dead-cwf tail ----
  if (c4 == 0) {
#pragma unroll
    for (int p = 0; p < 3; ++p) mi_s[p * 16 + ilg] = sqrtf(diiv[p] * md);
  }
  if (lane == 0) mi_s[48] = sqrtf(dii48 * md);

  // ---- Sm mfma + exp drain into Pb (aliases cwf, now dead) ----
#pragma unroll
  for (int rt = 0; rt < 4; ++rt) {
    f32x4 C[4];
#pragma unroll
    for (int ct = 0; ct < 4; ++ct) C[ct] = (f32x4)0.f;
#pragma unroll
    for (int ks = 0; ks < 2; ++ks) {
#pragma unroll
      for (int ct = 0; ct < 4; ++ct) {
        C[ct] = __builtin_amdgcn_mfma_f32_16x16x32_bf16(ah[rt][ks], ah[ct][ks], C[ct], 0, 0, 0);
        C[ct] = __builtin_amdgcn_mfma_f32_16x16x32_bf16(ah[rt][ks], al[ct][ks], C[ct], 0, 0, 0);
        C[ct] = __builtin_amdgcn_mfma_f32_16x16x32_bf16(al[rt][ks], ah[ct][ks], C[ct], 0, 0, 0);
      }
    }
    if (rt == 0) { asm volatile("s_waitcnt lgkmcnt(0)" ::: "memory"); }  // mi stores retired
#pragma unroll
    for (int reg = 0; reg < 4; ++reg) {
      int row = rt * 16 + lg * 4 + reg;
      float m = mi_s[(row < 49) ? row : 0];
#pragma unroll
      for (int ct = 0; ct < 4; ++ct) {
        float p = __expf(C[ct][reg] - m);
        if (row < 49) Pb[row * 72 + ct * 16 + lr] = f2bf(p);
      }
    }
  }
  asm volatile("" ::: "memory");  // Pb writes ordered before rowsum/PV reads

  // ---- motion row sums (over the bf16 values actually used) ----
  if (rowok) {
    const u32x4* pr = (const u32x4*)(Pb + il * 72);
    unsigned int uu[28];
#pragma unroll
    for (int w = 0; w < 7; ++w) *(u32x4*)&uu[4*w] = pr[w];
    float s = 0.f;
#pragma unroll
    for (int w = 0; w < 24; ++w)
      s += bf2f((unsigned short)(uu[w] & 0xffffu)) + bf2f((unsigned short)(uu[w] >> 16));
    s += bf2f((unsigned short)(uu[24] & 0xffffu));   // col 48
    scm[il] = 0.5f / s;
  }

  // ---- pack V fragments (hi/lo) from the hoisted raw loads ----
  bf16x8 vfh[2], vfl[2];
#pragma unroll
  for (int ks = 0; ks < 2; ++ks) {
    union { u32x4 u; bf16x8 s; } Hh, Ll;
#pragma unroll
    for (int p = 0; p < 4; ++p) {
      unsigned short h0 = f2bf(xv[ks][2*p]);
      unsigned short h1 = f2bf(xv[ks][2*p+1]);
      unsigned short l0 = f2bf(xv[ks][2*p]   - bf2f(h0));
      unsigned short l1 = f2bf(xv[ks][2*p+1] - bf2f(h1));
      Hh.u[p] = (unsigned int)h0 | ((unsigned int)h1 << 16);
      Ll.u[p] = (unsigned int)l0 | ((unsigned int)l1 << 16);
    }
    vfh[ks] = Hh.s;
    vfl[ks] = Ll.s;
  }

  // ---- motion PV ----
  f32x4 om[4];
#pragma unroll
  for (int rt = 0; rt < 4; ++rt) om[rt] = (f32x4)0.f;
#pragma unroll
  for (int ks = 0; ks < 2; ++ks) {
#pragma unroll
    for (int rt = 0; rt < 4; ++rt) {
      int row = rt * 16 + lr;
      int rowc = (row < 49) ? row : 0;
      bf16x8 pa = *(const bf16x8*)(Pb + rowc * 72 + ks * 32 + lg * 8);
      om[rt] = __builtin_amdgcn_mfma_f32_16x16x32_bf16(pa, vfh[ks], om[rt], 0, 0, 0);
      om[rt] = __builtin_amdgcn_mfma_f32_16x16x32_bf16(pa, vfl[ks], om[rt], 0, 0, 0);
    }
  }
  asm volatile("s_waitcnt lgkmcnt(0)" ::: "memory");  // motion Pb reads done before app overwrite

  // ---- appearance: qf fragments direct from global q + pos2 (batched 2 tiles) ----
  bf16x8 qf[4];
#pragma unroll
  for (int half = 0; half < 2; ++half) {
    f32x4 qa_[2], qb_[2], pa_[2], pb_[2];
#pragma unroll
    for (int u = 0; u < 2; ++u) {
      const int tt2 = half * 2 + u;
      int row = tt2 * 16 + lr;
      int rowc = (row < 49) ? row : 0;
      int a2 = (rowc * 37) >> 8;
      int b3 = rowc - a2 * 7;
      const int co = (lg & 1) * 8;
      const float* qsrc = qb + (size_t)((a2 * 8 + wy) * 56 + (b3 * 8 + wx)) * 16 + co;
      qa_[u] = *(const f32x4*)qsrc;
      qb_[u] = *(const f32x4*)(qsrc + 4);
      const float* p2 = pos2 + rowc * 16 + co;
      pa_[u] = *(const f32x4*)p2;
      pb_[u] = *(const f32x4*)(p2 + 4);
    }
#pragma unroll
    for (int u = 0; u < 2; ++u) {
      const int tt2 = half * 2 + u;
      int row = tt2 * 16 + lr;
      f32x4 w0 = qa_[u] + pa_[u], w1 = qb_[u] + pb_[u];
      float ws[8] = {w0.x, w0.y, w0.z, w0.w, w1.x, w1.y, w1.z, w1.w};
      const bool zv = (row >= 49) || (lg >= 2);
      union { u32x4 u4; bf16x8 s; } Q;
#pragma unroll
      for (int p = 0; p < 4; ++p) {
        unsigned int v = (unsigned)f2bf(ws[2*p]) | ((unsigned)f2bf(ws[2*p+1]) << 16);
        Q.u4[p] = zv ? 0u : v;
      }
      qf[tt2] = Q.s;
    }
  }

  // ---- appearance gram (K=16, plain bf16, shift 0) + exp drain ----
#pragma unroll
  for (int rt = 0; rt < 4; ++rt) {
    f32x4 Ca[4];
#pragma unroll
    for (int ct = 0; ct < 4; ++ct) Ca[ct] = (f32x4)0.f;
#pragma unroll
    for (int ct = 0; ct < 4; ++ct)
      Ca[ct] = __builtin_amdgcn_mfma_f32_16x16x32_bf16(qf[rt], qf[ct], Ca[ct], 0, 0, 0);
#pragma unroll
    for (int reg = 0; reg < 4; ++reg) {
      int row = rt * 16 + lg * 4 + reg;
#pragma unroll
      for (int ct = 0; ct < 4; ++ct) {
        float p = __expf(Ca[ct][reg]);
        if (row < 49) Pb[row * 72 + ct * 16 + lr] = f2bf(p);
      }
    }
  }
  asm volatile("" ::: "memory");  // app Pb writes ordered before reads

  // ---- appearance row sums ----
  if (rowok) {
    const u32x4* pr = (const u32x4*)(Pb + il * 72);
    unsigned int uu[28];
#pragma unroll
    for (int w = 0; w < 7; ++w) *(u32x4*)&uu[4*w] = pr[w];
    float s = 0.f;
#pragma unroll
    for (int w = 0; w < 24; ++w)
      s += bf2f((unsigned short)(uu[w] & 0xffffu)) + bf2f((unsigned short)(uu[w] >> 16));
    s += bf2f((unsigned short)(uu[24] & 0xffffu));
    sca[il] = 0.5f / s;
  }

  // ---- appearance PV ----
  f32x4 oa[4];
#pragma unroll
  for (int rt = 0; rt < 4; ++rt) oa[rt] = (f32x4)0.f;
#pragma unroll
  for (int ks = 0; ks < 2; ++ks) {
#pragma unroll
    for (int rt = 0; rt < 4; ++rt) {
      int row = rt * 16 + lr;
      int rowc = (row < 49) ? row : 0;
      bf16x8 pa = *(const bf16x8*)(Pb + rowc * 72 + ks * 32 + lg * 8);
      oa[rt] = __builtin_amdgcn_mfma_f32_16x16x32_bf16(pa, vfh[ks], oa[rt], 0, 0, 0);
      oa[rt] = __builtin_amdgcn_mfma_f32_16x16x32_bf16(pa, vfl[ks], oa[rt], 0, 0, 0);
    }
  }

  // ---- epilogue: out = om*scm[row] + oa*sca[row], write (B,N,C) layout ----
  {
    int b = bt >> 6, e = (bt >> 3) & 7, tt = bt & 7;
    size_t obase = ((size_t)(b * NPIX + tt * HW_)) * 128 + e * 16 + lr;
#pragma unroll
    for (int rt = 0; rt < 4; ++rt) {
#pragma unroll
      for (int reg = 0; reg < 4; ++reg) {
        int row = rt * 16 + lg * 4 + reg;
        if (row < 49) {
          float o = om[rt][reg] * scm[row] + oa[rt][reg] * sca[row];
          int a2 = (row * 37) >> 8;
          int b3 = row - a2 * 7;
          mid[obase + (size_t)((a2 * 8 + wy) * 56 + (b3 * 8 + wx)) * 128] = o;
        }
      }
    }
  }
}

// ---------------------------------------------------------------------------
extern "C" void kernel_launch(void* const* d_in, const int* in_sizes, int n_in,
                              void* d_out, int out_size, void* d_ws, size_t ws_size,
                              hipStream_t stream) {
  (void)in_sizes; (void)n_in; (void)out_size; (void)ws_size;
  const float* x      = (const float*)d_in[0];
  const float* qkv_w  = (const float*)d_in[1];
  const float* proj_w = (const float*)d_in[2];
  const float* proj_b = (const float*)d_in[3];
  const float* pos1   = (const float*)d_in[4];
  const float* pos2   = (const float*)d_in[5];
  float* out = (float*)d_out;

  float* qn = (float*)d_ws;
  float* kc = qn + SLAB;
  float* vv = kc + SLAB;

  gemm128<0><<<dim3(392, 3), 256, 0, stream>>>(x, qkv_w, nullptr, qn, kc, vv, nullptr);
  attn_mfma<<<dim3(8192), 64, 0, stream>>>(qn, kc, vv, pos1, pos2, out);
  gemm128<1><<<dim3(392), 256, 0, stream>>>(out, proj_w, proj_b, nullptr, nullptr, nullptr, out);
}

// Round 13
// 216.960 us; speedup vs baseline: 1.3730x; 1.1437x over previous
//
#include <hip/hip_runtime.h>
#include <math.h>

// Problem constants (B=2, T=8, H=W=56, C=128, heads=8, hd=16, WS=7, nh=nw=8)
constexpr int H_   = 56;
constexpr int HW_  = 56 * 56;          // 3136
constexpr int NPIX = 8 * HW_;          // 25088 (per batch)
constexpr int SLAB = 128 * HW_ * 16;   // floats per q/k/v buffer
constexpr int CWST = 52;               // cwpk row stride (u32)

typedef __attribute__((ext_vector_type(8))) short bf16x8;
typedef __attribute__((ext_vector_type(4))) float f32x4;
typedef __attribute__((ext_vector_type(4))) unsigned int u32x4;

__device__ __forceinline__ unsigned short f2bf(float x) {
  unsigned int u = __float_as_uint(x);
  unsigned int r = (u + 0x7fffu + ((u >> 16) & 1u)) >> 16;
  return (unsigned short)r;
}
__device__ __forceinline__ float bf2f(unsigned short h) {
  return __uint_as_float(((unsigned int)h) << 16);
}

// ---------------------------------------------------------------------------
// GEMM: unchanged (K1 qkv+l2norm+scatter, K3 proj). ~36-45us combined.
// ---------------------------------------------------------------------------
template <int MODE>
__global__ __launch_bounds__(256, 3) void gemm128(
    const float* X, const float* __restrict__ Wt, const float* __restrict__ bias,
    float* __restrict__ Yq, float* __restrict__ Yk, float* __restrict__ Yv,
    float* Yout)
{
  __shared__ float xT[32][132];
  __shared__ float wT[32][132];
  const int tid = threadIdx.x;
  const int tx = tid & 15, ty = tid >> 4;
  const int mbase = blockIdx.x * 128;
  const int nt = (MODE == 0) ? (int)blockIdx.y : 0;
  const float* Wp = Wt + (size_t)nt * (128 * 128);

  float acc[8][8];
#pragma unroll
  for (int i = 0; i < 8; ++i)
#pragma unroll
    for (int j = 0; j < 8; ++j) acc[i][j] = 0.f;

  const int srow = tid >> 3;
  const int scol = (tid & 7) * 4;

  for (int kt = 0; kt < 4; ++kt) {
    if (kt) __syncthreads();
#pragma unroll
    for (int p = 0; p < 4; ++p) {
      int r = p * 32 + srow;
      float4 vx = *(const float4*)&X [(size_t)(mbase + r) * 128 + kt * 32 + scol];
      float4 vw = *(const float4*)&Wp[(size_t)r * 128 + kt * 32 + scol];
      xT[scol + 0][r] = vx.x; xT[scol + 1][r] = vx.y; xT[scol + 2][r] = vx.z; xT[scol + 3][r] = vx.w;
      wT[scol + 0][r] = vw.x; wT[scol + 1][r] = vw.y; wT[scol + 2][r] = vw.z; wT[scol + 3][r] = vw.w;
    }
    __syncthreads();
#pragma unroll 4
    for (int c = 0; c < 32; ++c) {
      float4 a0 = *(const float4*)&xT[c][tx * 4];
      float4 a1 = *(const float4*)&xT[c][64 + tx * 4];
      float4 b0 = *(const float4*)&wT[c][ty * 4];
      float4 b1 = *(const float4*)&wT[c][64 + ty * 4];
      float a[8] = {a0.x, a0.y, a0.z, a0.w, a1.x, a1.y, a1.z, a1.w};
      float b[8] = {b0.x, b0.y, b0.z, b0.w, b1.x, b1.y, b1.z, b1.w};
#pragma unroll
      for (int i = 0; i < 8; ++i)
#pragma unroll
        for (int j = 0; j < 8; ++j) acc[i][j] += a[i] * b[j];
    }
  }

  if (MODE == 0) {
    const int hq = ty >> 2;
    const int cq = (ty & 3) * 4;
    float* Ybase = (nt == 0) ? Yq : ((nt == 1) ? Yk : Yv);
#pragma unroll
    for (int i = 0; i < 8; ++i) {
      int gpix = mbase + ((i < 4) ? (tx * 4 + i) : (64 + tx * 4 + (i - 4)));
      int b = gpix / NPIX;
      int rem = gpix - b * NPIX;
      int t = rem / HW_;
      int s = rem - t * HW_;
      float s0 = acc[i][0]*acc[i][0] + acc[i][1]*acc[i][1] + acc[i][2]*acc[i][2] + acc[i][3]*acc[i][3];
      float s1 = acc[i][4]*acc[i][4] + acc[i][5]*acc[i][5] + acc[i][6]*acc[i][6] + acc[i][7]*acc[i][7];
      s0 += __shfl_xor(s0, 16); s0 += __shfl_xor(s0, 32);
      s1 += __shfl_xor(s1, 16); s1 += __shfl_xor(s1, 32);
      float r0 = 1.f, r1 = 1.f;
      if (nt < 2) {
        r0 = 1.f / fmaxf(sqrtf(s0), 1e-12f);
        r1 = 1.f / fmaxf(sqrtf(s1), 1e-12f);
      }
      int bt0 = (b * 8 + hq) * 8 + t;
      int bt1 = (b * 8 + hq + 4) * 8 + t;
      float* d0 = Ybase + ((size_t)bt0 * HW_ + s) * 16 + cq;
      float* d1 = Ybase + ((size_t)bt1 * HW_ + s) * 16 + cq;
      *(float4*)d0 = make_float4(acc[i][0]*r0, acc[i][1]*r0, acc[i][2]*r0, acc[i][3]*r0);
      *(float4*)d1 = make_float4(acc[i][4]*r1, acc[i][5]*r1, acc[i][6]*r1, acc[i][7]*r1);
    }
  } else {
    float4 bb0 = *(const float4*)&bias[ty * 4];
    float4 bb1 = *(const float4*)&bias[64 + ty * 4];
#pragma unroll
    for (int i = 0; i < 8; ++i) {
      int gpix = mbase + ((i < 4) ? (tx * 4 + i) : (64 + tx * 4 + (i - 4)));
      float* dst = Yout + (size_t)gpix * 128;
      *(float4*)&dst[ty * 4]      = make_float4(acc[i][0]+bb0.x, acc[i][1]+bb0.y, acc[i][2]+bb0.z, acc[i][3]+bb0.w);
      *(float4*)&dst[64 + ty * 4] = make_float4(acc[i][4]+bb1.x, acc[i][5]+bb1.y, acc[i][6]+bb1.z, acc[i][7]+bb1.w);
    }
  }
}

// ---------------------------------------------------------------------------
// K2a: dense correlation. Window-independent: cw depends only on the pixel.
// Per bt, 4-row strips; k-halo (10 rows x 56 x 16 f32 = 35KB) staged in LDS;
// thread = pixel; computes 49 taps + pos1, dii, packs bf16 hi|lo<<16 u32 and
// writes rows of stride 52 u32 (16B-vectorized, 4 taps per store) + diib.
// Regular streaming kernel: removes the gather+DPP chain from every attn wave.
// ---------------------------------------------------------------------------
__global__ __launch_bounds__(256) void corr_dense(
    const float* __restrict__ qn, const float* __restrict__ kn,
    const float* __restrict__ pos1,
    unsigned int* __restrict__ cwpk, float* __restrict__ diib)
{
  __shared__ float kS[10][56][16];   // 35840 B
  const int bid = blockIdx.x;        // 1792 = 8 xcd * 16 bt * 14 strips
  const int xcd = bid & 7;
  const int j = bid >> 3;            // 0..223
  const int g = j / 14;
  const int strip = j - g * 14;
  const int bt = xcd * 16 + g;
  const int h0 = strip * 4;
  const int t = bt & 7;
  const int btk = bt - t + ((t < 7) ? (t + 1) : 7);
  const float* qb = qn + (size_t)bt  * (HW_ * 16);
  const float* kb = kn + (size_t)btk * (HW_ * 16);
  const int tid = threadIdx.x;

  // stage k rows h0-3 .. h0+6 (10 rows), zero OOB rows
  for (int idx = tid; idx < 2240; idx += 256) {
    int r = idx / 224;
    int c = idx - r * 224;
    int hh = h0 - 3 + r;
    f32x4 v = (f32x4)0.f;
    if ((unsigned)hh < 56u)
      v = *(const f32x4*)(kb + (size_t)(hh * 56) * 16 + c * 4);
    *(f32x4*)(&kS[r][0][0] + c * 4) = v;
  }
  __syncthreads();

  if (tid < 224) {
    const int py = tid / 56;
    const int h = h0 + py;
    const int w = tid - py * 56;
    const f32x4* qp = (const f32x4*)(qb + (size_t)(h * 56 + w) * 16);
    f32x4 q0 = qp[0], q1 = qp[1], q2 = qp[2], q3 = qp[3];
    const int ridx = (h >> 3) * 7 + (w >> 3);
    const float* p1r = pos1 + ridx * 49;
    unsigned int* outr = cwpk + (size_t)(bt * HW_ + h * 56 + w) * CWST;
    float dii = 0.f;
#pragma unroll
    for (int d4 = 0; d4 < 12; ++d4) {
      unsigned int pk[4];
#pragma unroll
      for (int e = 0; e < 4; ++e) {
        const int d = d4 * 4 + e;          // compile-time
        const int du = d / 7, dv = d % 7;  // compile-time
        const int ww = w + dv - 3;
        float val = 0.f;
        if (((unsigned)(h + du - 3) < 56u) && ((unsigned)ww < 56u)) {
          const f32x4* kp = (const f32x4*)&kS[py + du][ww][0];
          f32x4 a = q0 * kp[0] + q1 * kp[1] + q2 * kp[2] + q3 * kp[3];
          val = (a.x + a.y) + (a.z + a.w);
        }
        val += p1r[d];
        dii += val * val;
        unsigned short hb = f2bf(val);
        unsigned short lb = f2bf(val - bf2f(hb));
        pk[e] = (unsigned)hb | ((unsigned)lb << 16);
      }
      *(u32x4*)(outr + d4 * 4) = *(const u32x4*)pk;
    }
    { // d = 48 (du=6, dv=6)
      const int ww = w + 3;
      float val = 0.f;
      if (((unsigned)(h + 3) < 56u) && ((unsigned)ww < 56u)) {
        const f32x4* kp = (const f32x4*)&kS[py + 6][ww][0];
        f32x4 a = q0 * kp[0] + q1 * kp[1] + q2 * kp[2] + q3 * kp[3];
        val = (a.x + a.y) + (a.z + a.w);
      }
      val += p1r[48];
      dii += val * val;
      unsigned short hb = f2bf(val);
      unsigned short lb = f2bf(val - bf2f(hb));
      outr[48] = (unsigned)hb | ((unsigned)lb << 16);
    }
    diib[bt * HW_ + h * 56 + w] = dii;
  }
}

// ---------------------------------------------------------------------------
// K2b: MFMA window attention v11 -- corr phase removed. A-fragments load
// directly from precomputed cwpk (16 independent u32x4, L2-resident); dii is
// one load + wave max. LDS shrinks to 7.8KB (no aliasing). Downstream (split
// bf16 gram, Cauchy-Schwarz shift, Pb, PV, appearance-from-global, epilogue)
// identical to round 12.
// ---------------------------------------------------------------------------
__global__ __launch_bounds__(64, 2) void attn_mfma(
    const float* __restrict__ qn, const float* __restrict__ vv,
    const unsigned int* __restrict__ cwpk, const float* __restrict__ diib,
    const float* __restrict__ pos2, float* __restrict__ mid)
{
  __shared__ __align__(16) unsigned char smem[7808];
  unsigned short* Pb   = (unsigned short*)smem;       // [49][72] bf16 (7056 B)
  float*          mi_s = (float*)(smem + 7104);       // [49]
  float*          scm  = (float*)(smem + 7300);       // [49]
  float*          sca  = (float*)(smem + 7500);       // [49]

  const int lane = threadIdx.x;
  const int lg = lane >> 4;       // mfma k-group
  const int lr = lane & 15;       // mfma row/col within tile
  // XCD-aware remap (matches corr_dense's bt->XCD mapping)
  const int bid = blockIdx.x;
  const int xcd = bid & 7;
  const int j = bid >> 3;
  const int bt = xcd * 16 + (j >> 6);
  const int win = j & 63;
  const int wy = win >> 3;
  const int wx = win & 7;
  const float* qb = qn + (size_t)bt * (HW_ * 16);
  const float* vb = vv + (size_t)bt * (HW_ * 16);
  const unsigned int* cwb = cwpk + (size_t)bt * HW_ * CWST;
  const float* dib = diib + (size_t)bt * HW_;

  const bool rowok = (lane < 49);
  const int il = rowok ? lane : 48;

  // ---- V loads early (raw f32, packed later) ----
  float xv[2][8];
#pragma unroll
  for (int ks = 0; ks < 2; ++ks) {
#pragma unroll
    for (int e = 0; e < 8; ++e) {
      int k = ks * 32 + lg * 8 + e;
      int kc2 = (k < 49) ? k : 0;
      int ka = (kc2 * 37) >> 8;
      int kb2 = kc2 - ka * 7;
      float x = vb[(size_t)((ka * 8 + wy) * 56 + (kb2 * 8 + wx)) * 16 + lr];
      xv[ks][e] = (k < 49) ? x : 0.f;
    }
  }

  // ---- dii + Cauchy-Schwarz shift ----
  {
    const int ia = (il * 37) >> 8;
    const int ib = il - ia * 7;
    float dii = dib[(ia * 8 + wy) * 56 + (ib * 8 + wx)];
    float md = dii;
#pragma unroll
    for (int o = 32; o >= 1; o >>= 1) md = fmaxf(md, __shfl_xor(md, o));
    if (rowok) mi_s[il] = sqrtf(dii * md);
  }

  // ---- A-fragments direct from cwpk (batched: 2 row-tiles per batch) ----
  bf16x8 ah[4][2], al[4][2];
#pragma unroll
  for (int half = 0; half < 2; ++half) {
    u32x4 raw[2][2][2];   // [u][ks][16B-half]
#pragma unroll
    for (int u = 0; u < 2; ++u) {
      const int tt2 = half * 2 + u;
      const int row = tt2 * 16 + lr;
      const int rowc = (row < 49) ? row : 0;
      const int a2 = (rowc * 37) >> 8;
      const int b3 = rowc - a2 * 7;
      const unsigned int* src = cwb + (size_t)((a2 * 8 + wy) * 56 + (b3 * 8 + wx)) * CWST;
#pragma unroll
      for (int ks = 0; ks < 2; ++ks) {
        const int cb = ks * 32 + lg * 8;
        raw[u][ks][0] = *(const u32x4*)(src + cb);
        raw[u][ks][1] = *(const u32x4*)(src + cb + 4);
      }
    }
#pragma unroll
    for (int u = 0; u < 2; ++u) {
      const int tt2 = half * 2 + u;
      const int row = tt2 * 16 + lr;
      const bool rv = (row < 49);
#pragma unroll
      for (int ks = 0; ks < 2; ++ks) {
        const int cb = ks * 32 + lg * 8;
        unsigned int u0[8];
        *(u32x4*)&u0[0] = raw[u][ks][0];
        *(u32x4*)&u0[4] = raw[u][ks][1];
#pragma unroll
        for (int e = 0; e < 8; ++e)
          if (!rv || (cb + e) >= 49) u0[e] = 0u;
        union { u32x4 uu; bf16x8 s; } Hh, Ll;
#pragma unroll
        for (int p = 0; p < 4; ++p) {
          Hh.uu[p] = (u0[2*p] & 0xffffu) | (u0[2*p+1] << 16);
          Ll.uu[p] = (u0[2*p] >> 16) | (u0[2*p+1] & 0xffff0000u);
        }
        ah[tt2][ks] = Hh.s;
        al[tt2][ks] = Ll.s;
      }
    }
  }

  // ---- Sm mfma + exp drain into Pb ----
#pragma unroll
  for (int rt = 0; rt < 4; ++rt) {
    f32x4 C[4];
#pragma unroll
    for (int ct = 0; ct < 4; ++ct) C[ct] = (f32x4)0.f;
#pragma unroll
    for (int ks = 0; ks < 2; ++ks) {
#pragma unroll
      for (int ct = 0; ct < 4; ++ct) {
        C[ct] = __builtin_amdgcn_mfma_f32_16x16x32_bf16(ah[rt][ks], ah[ct][ks], C[ct], 0, 0, 0);
        C[ct] = __builtin_amdgcn_mfma_f32_16x16x32_bf16(ah[rt][ks], al[ct][ks], C[ct], 0, 0, 0);
        C[ct] = __builtin_amdgcn_mfma_f32_16x16x32_bf16(al[rt][ks], ah[ct][ks], C[ct], 0, 0, 0);
      }
    }
#pragma unroll
    for (int reg = 0; reg < 4; ++reg) {
      int row = rt * 16 + lg * 4 + reg;
      float m = mi_s[(row < 49) ? row : 0];
#pragma unroll
      for (int ct = 0; ct < 4; ++ct) {
        float p = __expf(C[ct][reg] - m);
        if (row < 49) Pb[row * 72 + ct * 16 + lr] = f2bf(p);
      }
    }
  }
  asm volatile("" ::: "memory");  // Pb writes ordered before rowsum/PV reads

  // ---- motion row sums ----
  if (rowok) {
    const u32x4* pr = (const u32x4*)(Pb + il * 72);
    unsigned int uu[28];
#pragma unroll
    for (int w = 0; w < 7; ++w) *(u32x4*)&uu[4*w] = pr[w];
    float s = 0.f;
#pragma unroll
    for (int w = 0; w < 24; ++w)
      s += bf2f((unsigned short)(uu[w] & 0xffffu)) + bf2f((unsigned short)(uu[w] >> 16));
    s += bf2f((unsigned short)(uu[24] & 0xffffu));
    scm[il] = 0.5f / s;
  }

  // ---- pack V fragments (hi/lo) ----
  bf16x8 vfh[2], vfl[2];
#pragma unroll
  for (int ks = 0; ks < 2; ++ks) {
    union { u32x4 u; bf16x8 s; } Hh, Ll;
#pragma unroll
    for (int p = 0; p < 4; ++p) {
      unsigned short h0 = f2bf(xv[ks][2*p]);
      unsigned short h1 = f2bf(xv[ks][2*p+1]);
      unsigned short l0 = f2bf(xv[ks][2*p]   - bf2f(h0));
      unsigned short l1 = f2bf(xv[ks][2*p+1] - bf2f(h1));
      Hh.u[p] = (unsigned int)h0 | ((unsigned int)h1 << 16);
      Ll.u[p] = (unsigned int)l0 | ((unsigned int)l1 << 16);
    }
    vfh[ks] = Hh.s;
    vfl[ks] = Ll.s;
  }

  // ---- motion PV ----
  f32x4 om[4];
#pragma unroll
  for (int rt = 0; rt < 4; ++rt) om[rt] = (f32x4)0.f;
#pragma unroll
  for (int ks = 0; ks < 2; ++ks) {
#pragma unroll
    for (int rt = 0; rt < 4; ++rt) {
      int row = rt * 16 + lr;
      int rowc = (row < 49) ? row : 0;
      bf16x8 pa = *(const bf16x8*)(Pb + rowc * 72 + ks * 32 + lg * 8);
      om[rt] = __builtin_amdgcn_mfma_f32_16x16x32_bf16(pa, vfh[ks], om[rt], 0, 0, 0);
      om[rt] = __builtin_amdgcn_mfma_f32_16x16x32_bf16(pa, vfl[ks], om[rt], 0, 0, 0);
    }
  }
  asm volatile("s_waitcnt lgkmcnt(0)" ::: "memory");  // motion Pb reads done before app overwrite

  // ---- appearance: qf fragments direct from global q + pos2 ----
  bf16x8 qf[4];
#pragma unroll
  for (int half = 0; half < 2; ++half) {
    f32x4 qa_[2], qb_[2], pa_[2], pb_[2];
#pragma unroll
    for (int u = 0; u < 2; ++u) {
      const int tt2 = half * 2 + u;
      int row = tt2 * 16 + lr;
      int rowc = (row < 49) ? row : 0;
      int a2 = (rowc * 37) >> 8;
      int b3 = rowc - a2 * 7;
      const int co = (lg & 1) * 8;
      const float* qsrc = qb + (size_t)((a2 * 8 + wy) * 56 + (b3 * 8 + wx)) * 16 + co;
      qa_[u] = *(const f32x4*)qsrc;
      qb_[u] = *(const f32x4*)(qsrc + 4);
      const float* p2 = pos2 + rowc * 16 + co;
      pa_[u] = *(const f32x4*)p2;
      pb_[u] = *(const f32x4*)(p2 + 4);
    }
#pragma unroll
    for (int u = 0; u < 2; ++u) {
      const int tt2 = half * 2 + u;
      int row = tt2 * 16 + lr;
      f32x4 w0 = qa_[u] + pa_[u], w1 = qb_[u] + pb_[u];
      float ws[8] = {w0.x, w0.y, w0.z, w0.w, w1.x, w1.y, w1.z, w1.w};
      const bool zv = (row >= 49) || (lg >= 2);
      union { u32x4 u4; bf16x8 s; } Q;
#pragma unroll
      for (int p = 0; p < 4; ++p) {
        unsigned int v = (unsigned)f2bf(ws[2*p]) | ((unsigned)f2bf(ws[2*p+1]) << 16);
        Q.u4[p] = zv ? 0u : v;
      }
      qf[tt2] = Q.s;
    }
  }

  // ---- appearance gram (K=16, plain bf16, shift 0) + exp drain ----
#pragma unroll
  for (int rt = 0; rt < 4; ++rt) {
    f32x4 Ca[4];
#pragma unroll
    for (int ct = 0; ct < 4; ++ct) Ca[ct] = (f32x4)0.f;
#pragma unroll
    for (int ct = 0; ct < 4; ++ct)
      Ca[ct] = __builtin_amdgcn_mfma_f32_16x16x32_bf16(qf[rt], qf[ct], Ca[ct], 0, 0, 0);
#pragma unroll
    for (int reg = 0; reg < 4; ++reg) {
      int row = rt * 16 + lg * 4 + reg;
#pragma unroll
      for (int ct = 0; ct < 4; ++ct) {
        float p = __expf(Ca[ct][reg]);
        if (row < 49) Pb[row * 72 + ct * 16 + lr] = f2bf(p);
      }
    }
  }
  asm volatile("" ::: "memory");  // app Pb writes ordered before reads

  // ---- appearance row sums ----
  if (rowok) {
    const u32x4* pr = (const u32x4*)(Pb + il * 72);
    unsigned int uu[28];
#pragma unroll
    for (int w = 0; w < 7; ++w) *(u32x4*)&uu[4*w] = pr[w];
    float s = 0.f;
#pragma unroll
    for (int w = 0; w < 24; ++w)
      s += bf2f((unsigned short)(uu[w] & 0xffffu)) + bf2f((unsigned short)(uu[w] >> 16));
    s += bf2f((unsigned short)(uu[24] & 0xffffu));
    sca[il] = 0.5f / s;
  }

  // ---- appearance PV ----
  f32x4 oa[4];
#pragma unroll
  for (int rt = 0; rt < 4; ++rt) oa[rt] = (f32x4)0.f;
#pragma unroll
  for (int ks = 0; ks < 2; ++ks) {
#pragma unroll
    for (int rt = 0; rt < 4; ++rt) {
      int row = rt * 16 + lr;
      int rowc = (row < 49) ? row : 0;
      bf16x8 pa = *(const bf16x8*)(Pb + rowc * 72 + ks * 32 + lg * 8);
      oa[rt] = __builtin_amdgcn_mfma_f32_16x16x32_bf16(pa, vfh[ks], oa[rt], 0, 0, 0);
      oa[rt] = __builtin_amdgcn_mfma_f32_16x16x32_bf16(pa, vfl[ks], oa[rt], 0, 0, 0);
    }
  }

  // ---- epilogue: out = om*scm[row] + oa*sca[row], write (B,N,C) layout ----
  {
    int b = bt >> 6, e = (bt >> 3) & 7, tt = bt & 7;
    size_t obase = ((size_t)(b * NPIX + tt * HW_)) * 128 + e * 16 + lr;
#pragma unroll
    for (int rt = 0; rt < 4; ++rt) {
#pragma unroll
      for (int reg = 0; reg < 4; ++reg) {
        int row = rt * 16 + lg * 4 + reg;
        if (row < 49) {
          float o = om[rt][reg] * scm[row] + oa[rt][reg] * sca[row];
          int a2 = (row * 37) >> 8;
          int b3 = row - a2 * 7;
          mid[obase + (size_t)((a2 * 8 + wy) * 56 + (b3 * 8 + wx)) * 128] = o;
        }
      }
    }
  }
}

// ---------------------------------------------------------------------------
extern "C" void kernel_launch(void* const* d_in, const int* in_sizes, int n_in,
                              void* d_out, int out_size, void* d_ws, size_t ws_size,
                              hipStream_t stream) {
  (void)in_sizes; (void)n_in; (void)out_size; (void)ws_size;
  const float* x      = (const float*)d_in[0];
  const float* qkv_w  = (const float*)d_in[1];
  const float* proj_w = (const float*)d_in[2];
  const float* proj_b = (const float*)d_in[3];
  const float* pos1   = (const float*)d_in[4];
  const float* pos2   = (const float*)d_in[5];
  float* out = (float*)d_out;

  float* qn = (float*)d_ws;                               // SLAB f32
  float* kc = qn + SLAB;                                  // SLAB f32
  float* vv = kc + SLAB;                                  // SLAB f32
  unsigned int* cwpk = (unsigned int*)(vv + SLAB);        // 128*HW_*52 u32 (+pad)
  float* diib = (float*)(cwpk + (size_t)128 * HW_ * CWST + 64);  // 128*HW_ f32

  // K1: QKV GEMM + per-head l2norm + scatter
  gemm128<0><<<dim3(392, 3), 256, 0, stream>>>(x, qkv_w, nullptr, qn, kc, vv, nullptr);
  // K2a: dense correlation (bf16 hi/lo packed) + dii
  corr_dense<<<dim3(1792), 256, 0, stream>>>(qn, kc, pos1, cwpk, diib);
  // K2b: window attention from precomputed corr
  attn_mfma<<<dim3(8192), 64, 0, stream>>>(qn, vv, cwpk, diib, pos2, out);
  // K3: output projection, in-place
  gemm128<1><<<dim3(392), 256, 0, stream>>>(out, proj_w, proj_b, nullptr, nullptr, nullptr, out);
}